// Round 1
// baseline (400.518 us; speedup 1.0000x reference)
//
#include <hip/hip_runtime.h>

#define S_LEN 4096
#define HID   2048
#define NHEAD 16
#define HDIM  128
#define QSCALE 0.08838834764831845f   // 1/sqrt(128)

typedef float  f32x4  __attribute__((ext_vector_type(4)));
typedef __bf16 bf16x8 __attribute__((ext_vector_type(8)));

#define MFMA16(a, b, c) __builtin_amdgcn_mfma_f32_16x16x32_bf16((a), (b), (c), 0, 0, 0)

__device__ __forceinline__ void gld16(const void* g, void* l) {
  __builtin_amdgcn_global_load_lds(
      (const __attribute__((address_space(1))) void*)(unsigned long long)(g),
      (__attribute__((address_space(3))) void*)(unsigned long long)(l),
      16, 0, 0);
}

__device__ __forceinline__ unsigned short f2bf(float f) {
  union { float f; unsigned u; } v; v.f = f;
  unsigned r = v.u + 0x7FFFu + ((v.u >> 16) & 1u);
  return (unsigned short)(r >> 16);
}
__device__ __forceinline__ float bf2f(unsigned short h) {
  union { unsigned u; float f; } v; v.u = ((unsigned)h) << 16;
  return v.f;
}

// ---------------- f32 -> bf16 conversion ----------------
__global__ __launch_bounds__(256) void cvt_kernel(const float* __restrict__ src,
                                                  unsigned short* __restrict__ dst, int n) {
  int i = (blockIdx.x * 256 + threadIdx.x) * 4;
  if (i >= n) return;
  const float4 v = *(const float4*)(src + i);
  ushort4 o;
  o.x = f2bf(v.x); o.y = f2bf(v.y); o.z = f2bf(v.z); o.w = f2bf(v.w);
  *(ushort4*)(dst + i) = o;
}

// ---------------- QKV GEMM: C[4096,6144] = hidden[4096,2048] . wqkv[6144,2048]^T
// epilogue scatters into Q [np][s][128] (scaled), K [np][s][128], Vt [np][128][s]
__global__ __launch_bounds__(256, 3) void gemm_qkv_kernel(
    const unsigned short* __restrict__ A, const unsigned short* __restrict__ B,
    unsigned short* __restrict__ Qb, unsigned short* __restrict__ Kb,
    unsigned short* __restrict__ Vt) {
  __shared__ __align__(16) unsigned short As[2][128 * 32];
  __shared__ __align__(16) unsigned short Bs[2][128 * 32];
  const int K = HID;
  const int bid = ((int)blockIdx.x % 8) * 192 + (int)blockIdx.x / 8;  // XCD swizzle (1536%8==0)
  const int bm = bid / 48, bn = bid % 48;
  const int row0 = bm * 128, col0 = bn * 128;
  const int tid = threadIdx.x;
  const int wid = tid >> 6, lane = tid & 63;
  const int g = lane >> 4, r16 = lane & 15;
  const int wr = wid >> 1, wc = wid & 1;

  f32x4 acc[4][4] = {};

  int srow[2], scol[2];
#pragma unroll
  for (int c = 0; c < 2; ++c) {
    int byteoff = (wid * 2 + c) * 1024 + lane * 16;
    srow[c] = byteoff >> 6;          // row within 128-tile (64B per row of 32 bf16)
    scol[c] = (byteoff & 63) >> 1;   // element offset in k
  }

  auto stage = [&](int buf, int t) {
    const int k0 = t * 32;
#pragma unroll
    for (int c = 0; c < 2; ++c) {
      gld16(A + (row0 + srow[c]) * K + k0 + scol[c], &As[buf][(wid * 2 + c) * 512]);
      gld16(B + (col0 + srow[c]) * K + k0 + scol[c], &Bs[buf][(wid * 2 + c) * 512]);
    }
  };

  const int nt = K / 32;
  stage(0, 0);
  __syncthreads();
  for (int t = 0; t < nt; ++t) {
    const int cur = t & 1;
    if (t + 1 < nt) stage(cur ^ 1, t + 1);
    const char* as = (const char*)As[cur];
    const char* bs = (const char*)Bs[cur];
    bf16x8 af[4], bfv[4];
#pragma unroll
    for (int m = 0; m < 4; ++m)
      af[m] = *(const bf16x8*)(as + (wr * 64 + m * 16 + r16) * 64 + g * 16);
#pragma unroll
    for (int n = 0; n < 4; ++n)
      bfv[n] = *(const bf16x8*)(bs + (wc * 64 + n * 16 + r16) * 64 + g * 16);
#pragma unroll
    for (int m = 0; m < 4; ++m)
#pragma unroll
      for (int n = 0; n < 4; ++n)
        acc[m][n] = MFMA16(af[m], bfv[n], acc[m][n]);
    __syncthreads();
  }

  // epilogue: each 128-wide n-tile is exactly one of {Q,K,V} for one head
  const int type = bn % 3, p = bn / 3;
#pragma unroll
  for (int m = 0; m < 4; ++m) {
    const int s0 = row0 + wr * 64 + m * 16 + g * 4;
#pragma unroll
    for (int n = 0; n < 4; ++n) {
      const int d = wc * 64 + n * 16 + r16;
      if (type == 0) {
#pragma unroll
        for (int r = 0; r < 4; ++r)
          Qb[(p * S_LEN + s0 + r) * HDIM + d] = f2bf(acc[m][n][r] * QSCALE);
      } else if (type == 1) {
#pragma unroll
        for (int r = 0; r < 4; ++r)
          Kb[(p * S_LEN + s0 + r) * HDIM + d] = f2bf(acc[m][n][r]);
      } else {
        ushort4 o;
        o.x = f2bf(acc[m][n][0]); o.y = f2bf(acc[m][n][1]);
        o.z = f2bf(acc[m][n][2]); o.w = f2bf(acc[m][n][3]);
        *(ushort4*)(Vt + (p * HDIM + d) * S_LEN + s0) = o;  // s0 % 4 == 0
      }
    }
  }
}

// ---------------- partial RoPE (NeoX, first 32 dims), in place on Q and K ----------------
__global__ __launch_bounds__(256) void rope_kernel(unsigned short* __restrict__ Qb,
                                                   unsigned short* __restrict__ Kb) {
  const int idx = blockIdx.x * 256 + threadIdx.x;       // 16 * 4096 * 16
  const int p = idx >> 16, rem = idx & 65535, s = rem >> 4, d = rem & 15;
  const float invf = exp2f(-(float)d * (13.287712379549449f / 16.0f));  // 10000^(-d/16)
  const float ang = (float)s * invf;
  const float c = cosf(ang), sn = sinf(ang);
  const int base = (p * S_LEN + s) * HDIM;
  {
    float x = bf2f(Qb[base + d]), y = bf2f(Qb[base + d + 16]);
    Qb[base + d]      = f2bf(x * c - y * sn);
    Qb[base + d + 16] = f2bf(y * c + x * sn);
  }
  {
    float x = bf2f(Kb[base + d]), y = bf2f(Kb[base + d + 16]);
    Kb[base + d]      = f2bf(x * c - y * sn);
    Kb[base + d + 16] = f2bf(y * c + x * sn);
  }
}

// ---------------- causal flash attention ----------------
// grid (32, 16): y = head, x paired so block handles q-tiles b and 63-b (uniform 65 kv-iters)
__global__ __launch_bounds__(256, 2) void attn_kernel(
    const unsigned short* __restrict__ Qb, const unsigned short* __restrict__ Kb,
    const unsigned short* __restrict__ Vt, unsigned short* __restrict__ Ctx) {
  __shared__ __align__(16) unsigned char sm[73728];  // K 2x16K | Vt 2x16K | P 4x2K
  unsigned char* const Kl0 = sm;
  unsigned char* const Vl0 = sm + 32768;
  const int p = blockIdx.y;
  const int tid = threadIdx.x, wid = tid >> 6, lane = tid & 63;
  const int g = lane >> 4, r16 = lane & 15;
  unsigned char* const Pl = sm + 65536 + wid * 2048;

  auto stageKV = [&](int buf, int t) {
    const unsigned short* kb = Kb + (p * S_LEN + t * 64) * HDIM;
    const unsigned short* vb = Vt + p * HDIM * S_LEN + t * 64;
#pragma unroll
    for (int c = 0; c < 4; ++c) {
      const int chunk = wid * 4 + c;
      const int byteoff = chunk * 1024 + lane * 16;
      {  // K tile [64][128], row 256B = 16 chunks, source pre-swizzled: c ^= (row&7)
        const int j = byteoff >> 8, cb = (byteoff >> 4) & 15;
        gld16(kb + j * HDIM + (cb ^ (j & 7)) * 8, Kl0 + buf * 16384 + chunk * 1024);
      }
      {  // Vt tile [128][64], row 128B = 8 chunks
        const int dd = byteoff >> 7, cb = (byteoff >> 4) & 7;
        gld16(vb + dd * S_LEN + (cb ^ (dd & 7)) * 8, Vl0 + buf * 16384 + chunk * 1024);
      }
    }
  };

  for (int sel = 0; sel < 2; ++sel) {
    const int qt = (sel == 0) ? (int)blockIdx.x : 63 - (int)blockIdx.x;
    const int q0 = qt * 64;
    const int nt = qt + 1;

    bf16x8 qf[4];
    {
      const unsigned short* qb = Qb + (p * S_LEN + q0 + wid * 16 + r16) * HDIM + g * 8;
#pragma unroll
      for (int kc = 0; kc < 4; ++kc) qf[kc] = *(const bf16x8*)(qb + kc * 32);
    }
    f32x4 acc[8] = {};
    float m_s[4], l_s[4];
#pragma unroll
    for (int r = 0; r < 4; ++r) { m_s[r] = -1e30f; l_s[r] = 0.f; }

    stageKV(0, 0);
    __syncthreads();
    for (int t = 0; t < nt; ++t) {
      const int cur = t & 1;
      if (t + 1 < nt) stageKV(cur ^ 1, t + 1);
      const unsigned char* kl = Kl0 + cur * 16384;
      const unsigned char* vl = Vl0 + cur * 16384;

      // S = Q . K^T  (16 rows x 64 cols per wave)
      f32x4 sv[4];
#pragma unroll
      for (int jb = 0; jb < 4; ++jb) {
        f32x4 z = {0.f, 0.f, 0.f, 0.f};
        const int j = jb * 16 + r16;
        const unsigned char* kr = kl + j * 256;
#pragma unroll
        for (int kc = 0; kc < 4; ++kc) {
          bf16x8 kf = *(const bf16x8*)(kr + ((kc * 64 + g * 16) ^ ((j & 7) << 4)));
          z = MFMA16(qf[kc], kf, z);
        }
        sv[jb] = z;
      }
      // causal mask
      const int i0 = q0 + wid * 16 + g * 4;
#pragma unroll
      for (int jb = 0; jb < 4; ++jb) {
        const int jg = t * 64 + jb * 16 + r16;
#pragma unroll
        for (int r = 0; r < 4; ++r)
          if (jg > i0 + r) sv[jb][r] = -1e30f;
      }
      // row max (reduce over 16 lanes of each group)
      float pm[4];
#pragma unroll
      for (int r = 0; r < 4; ++r)
        pm[r] = fmaxf(fmaxf(sv[0][r], sv[1][r]), fmaxf(sv[2][r], sv[3][r]));
#pragma unroll
      for (int mk = 1; mk <= 8; mk <<= 1)
#pragma unroll
        for (int r = 0; r < 4; ++r) pm[r] = fmaxf(pm[r], __shfl_xor(pm[r], mk, 64));
      float mn[4], scl[4], rs[4];
#pragma unroll
      for (int r = 0; r < 4; ++r) {
        mn[r] = fmaxf(m_s[r], pm[r]);
        scl[r] = __expf(m_s[r] - mn[r]);
        m_s[r] = mn[r];
        rs[r] = 0.f;
      }
      // P = exp(S - m), stash bf16 into per-wave swizzled LDS
#pragma unroll
      for (int jb = 0; jb < 4; ++jb)
#pragma unroll
        for (int r = 0; r < 4; ++r) {
          const float pv = __expf(sv[jb][r] - mn[r]);
          rs[r] += pv;
          const int prow = g * 4 + r;
          *(unsigned short*)(Pl + prow * 128 +
                             (((jb * 16 + r16) * 2) ^ ((prow & 7) << 4))) = f2bf(pv);
        }
#pragma unroll
      for (int mk = 1; mk <= 8; mk <<= 1)
#pragma unroll
        for (int r = 0; r < 4; ++r) rs[r] += __shfl_xor(rs[r], mk, 64);
#pragma unroll
      for (int r = 0; r < 4; ++r) l_s[r] = l_s[r] * scl[r] + rs[r];
#pragma unroll
      for (int nb = 0; nb < 8; ++nb)
#pragma unroll
        for (int r = 0; r < 4; ++r) acc[nb][r] *= scl[r];
      // ctx += P . V
#pragma unroll
      for (int kc = 0; kc < 2; ++kc) {
        bf16x8 pa = *(const bf16x8*)(Pl + r16 * 128 + ((kc * 64 + g * 16) ^ ((r16 & 7) << 4)));
#pragma unroll
        for (int nb = 0; nb < 8; ++nb) {
          const int d = nb * 16 + r16;
          bf16x8 vf = *(const bf16x8*)(vl + d * 128 + ((kc * 64 + g * 16) ^ ((d & 7) << 4)));
          acc[nb] = MFMA16(pa, vf, acc[nb]);
        }
      }
      __syncthreads();
    }
    // write ctx [s][2048] bf16
#pragma unroll
    for (int nb = 0; nb < 8; ++nb)
#pragma unroll
      for (int r = 0; r < 4; ++r) {
        const int srow = q0 + wid * 16 + g * 4 + r;
        Ctx[srow * HID + p * HDIM + nb * 16 + r16] = f2bf(acc[nb][r] / l_s[r]);
      }
  }
}

// ---------------- dense GEMM: out[4096,2048] = ctx . wdense^T + bias (f32 out) ----------------
__global__ __launch_bounds__(256, 3) void gemm_dense_kernel(
    const unsigned short* __restrict__ A, const unsigned short* __restrict__ B,
    const float* __restrict__ bias, float* __restrict__ out) {
  __shared__ __align__(16) unsigned short As[2][128 * 32];
  __shared__ __align__(16) unsigned short Bs[2][128 * 32];
  const int K = HID;
  const int bid = ((int)blockIdx.x % 8) * 64 + (int)blockIdx.x / 8;  // XCD swizzle (512%8==0)
  const int bm = bid / 16, bn = bid % 16;
  const int row0 = bm * 128, col0 = bn * 128;
  const int tid = threadIdx.x;
  const int wid = tid >> 6, lane = tid & 63;
  const int g = lane >> 4, r16 = lane & 15;
  const int wr = wid >> 1, wc = wid & 1;

  f32x4 acc[4][4] = {};

  int srow[2], scol[2];
#pragma unroll
  for (int c = 0; c < 2; ++c) {
    int byteoff = (wid * 2 + c) * 1024 + lane * 16;
    srow[c] = byteoff >> 6;
    scol[c] = (byteoff & 63) >> 1;
  }
  auto stage = [&](int buf, int t) {
    const int k0 = t * 32;
#pragma unroll
    for (int c = 0; c < 2; ++c) {
      gld16(A + (row0 + srow[c]) * K + k0 + scol[c], &As[buf][(wid * 2 + c) * 512]);
      gld16(B + (col0 + srow[c]) * K + k0 + scol[c], &Bs[buf][(wid * 2 + c) * 512]);
    }
  };

  const int nt = K / 32;
  stage(0, 0);
  __syncthreads();
  for (int t = 0; t < nt; ++t) {
    const int cur = t & 1;
    if (t + 1 < nt) stage(cur ^ 1, t + 1);
    const char* as = (const char*)As[cur];
    const char* bs = (const char*)Bs[cur];
    bf16x8 af[4], bfv[4];
#pragma unroll
    for (int m = 0; m < 4; ++m)
      af[m] = *(const bf16x8*)(as + (wr * 64 + m * 16 + r16) * 64 + g * 16);
#pragma unroll
    for (int n = 0; n < 4; ++n)
      bfv[n] = *(const bf16x8*)(bs + (wc * 64 + n * 16 + r16) * 64 + g * 16);
#pragma unroll
    for (int m = 0; m < 4; ++m)
#pragma unroll
      for (int n = 0; n < 4; ++n)
        acc[m][n] = MFMA16(af[m], bfv[n], acc[m][n]);
    __syncthreads();
  }

#pragma unroll
  for (int m = 0; m < 4; ++m) {
    const int s0 = row0 + wr * 64 + m * 16 + g * 4;
#pragma unroll
    for (int n = 0; n < 4; ++n) {
      const int col = col0 + wc * 64 + n * 16 + r16;
      const float bv = bias[col];
#pragma unroll
      for (int r = 0; r < 4; ++r)
        out[(s0 + r) * HID + col] = acc[m][n][r] + bv;
    }
  }
}

extern "C" void kernel_launch(void* const* d_in, const int* in_sizes, int n_in,
                              void* d_out, int out_size, void* d_ws, size_t ws_size,
                              hipStream_t stream) {
  (void)in_sizes; (void)n_in; (void)out_size; (void)ws_size;
  const float* hidden = (const float*)d_in[0];
  // d_in[1] = attention_mask: deterministic causal triu(k=1); hard-coded in attn_kernel
  const float* wqkv   = (const float*)d_in[2];
  const float* wdense = (const float*)d_in[3];
  const float* bdense = (const float*)d_in[4];
  float* out = (float*)d_out;

  char* ws = (char*)d_ws;
  unsigned short* hiddenB = (unsigned short*)(ws);              // 16 MB
  unsigned short* wqkvB   = (unsigned short*)(ws + 16777216);   // 24 MB
  unsigned short* wdenseB = (unsigned short*)(ws + 41943040);   //  8 MB
  unsigned short* Qb      = (unsigned short*)(ws + 50331648);   // 16 MB [np][s][128]
  unsigned short* Kb      = (unsigned short*)(ws + 67108864);   // 16 MB [np][s][128]
  unsigned short* Vt      = (unsigned short*)(ws + 83886080);   // 16 MB [np][128][s]
  unsigned short* ctxB    = (unsigned short*)(ws + 100663296);  // 16 MB [s][2048]

  cvt_kernel<<<8192, 256, 0, stream>>>(hidden, hiddenB, 8388608);
  cvt_kernel<<<12288, 256, 0, stream>>>(wqkv, wqkvB, 12582912);
  cvt_kernel<<<4096, 256, 0, stream>>>(wdense, wdenseB, 4194304);
  gemm_qkv_kernel<<<1536, 256, 0, stream>>>(hiddenB, wqkvB, Qb, Kb, Vt);
  rope_kernel<<<4096, 256, 0, stream>>>(Qb, Kb);
  attn_kernel<<<dim3(32, 16), 256, 0, stream>>>(Qb, Kb, Vt, ctxB);
  gemm_dense_kernel<<<512, 256, 0, stream>>>(ctxB, wdenseB, bdense, out);
}

// Round 2
// 365.665 us; speedup vs baseline: 1.0953x; 1.0953x over previous
//
#include <hip/hip_runtime.h>

#define S_LEN 4096
#define HID   2048
#define NHEAD 16
#define HDIM  128
// 1/sqrt(128) * log2(e): Q pre-scale so softmax can use exp2 directly
#define QSCALE_L2E 0.12751664352f

typedef float  f32x4  __attribute__((ext_vector_type(4)));
typedef float  f32x16 __attribute__((ext_vector_type(16)));
typedef __bf16 bf16x8 __attribute__((ext_vector_type(8)));
typedef unsigned u32x4 __attribute__((ext_vector_type(4)));

#define MFMA16(a, b, c) __builtin_amdgcn_mfma_f32_16x16x32_bf16((a), (b), (c), 0, 0, 0)
#define MFMA32(a, b, c) __builtin_amdgcn_mfma_f32_32x32x16_bf16((a), (b), (c), 0, 0, 0)

__device__ __forceinline__ void gld16(const void* g, void* l) {
  __builtin_amdgcn_global_load_lds(
      (const __attribute__((address_space(1))) void*)(unsigned long long)(g),
      (__attribute__((address_space(3))) void*)(unsigned long long)(l),
      16, 0, 0);
}

__device__ __forceinline__ unsigned short f2bf(float f) {
  union { float f; unsigned u; } v; v.f = f;
  unsigned r = v.u + 0x7FFFu + ((v.u >> 16) & 1u);
  return (unsigned short)(r >> 16);
}
__device__ __forceinline__ float bf2f(unsigned short h) {
  union { unsigned u; float f; } v; v.u = ((unsigned)h) << 16;
  return v.f;
}
__device__ __forceinline__ unsigned cvtpk_bf16(float a, float b) {
  unsigned r;
  asm("v_cvt_pk_bf16_f32 %0, %1, %2" : "=v"(r) : "v"(a), "v"(b));
  return r;
}

// ---------------- f32 -> bf16 conversion ----------------
__global__ __launch_bounds__(256) void cvt_kernel(const float* __restrict__ src,
                                                  unsigned short* __restrict__ dst, int n) {
  int i = (blockIdx.x * 256 + threadIdx.x) * 4;
  if (i >= n) return;
  const float4 v = *(const float4*)(src + i);
  ushort4 o;
  o.x = f2bf(v.x); o.y = f2bf(v.y); o.z = f2bf(v.z); o.w = f2bf(v.w);
  *(ushort4*)(dst + i) = o;
}

// ---------------- QKV GEMM: C[4096,6144] = hidden[4096,2048] . wqkv[6144,2048]^T
__global__ __launch_bounds__(256, 3) void gemm_qkv_kernel(
    const unsigned short* __restrict__ A, const unsigned short* __restrict__ B,
    unsigned short* __restrict__ Qb, unsigned short* __restrict__ Kb,
    unsigned short* __restrict__ Vt) {
  __shared__ __align__(16) unsigned short As[2][128 * 32];
  __shared__ __align__(16) unsigned short Bs[2][128 * 32];
  const int K = HID;
  const int bid = ((int)blockIdx.x % 8) * 192 + (int)blockIdx.x / 8;
  const int bm = bid / 48, bn = bid % 48;
  const int row0 = bm * 128, col0 = bn * 128;
  const int tid = threadIdx.x;
  const int wid = tid >> 6, lane = tid & 63;
  const int g = lane >> 4, r16 = lane & 15;
  const int wr = wid >> 1, wc = wid & 1;

  f32x4 acc[4][4] = {};

  int srow[2], scol[2];
#pragma unroll
  for (int c = 0; c < 2; ++c) {
    int byteoff = (wid * 2 + c) * 1024 + lane * 16;
    srow[c] = byteoff >> 6;
    scol[c] = (byteoff & 63) >> 1;
  }

  auto stage = [&](int buf, int t) {
    const int k0 = t * 32;
#pragma unroll
    for (int c = 0; c < 2; ++c) {
      gld16(A + (row0 + srow[c]) * K + k0 + scol[c], &As[buf][(wid * 2 + c) * 512]);
      gld16(B + (col0 + srow[c]) * K + k0 + scol[c], &Bs[buf][(wid * 2 + c) * 512]);
    }
  };

  const int nt = K / 32;
  stage(0, 0);
  __syncthreads();
  for (int t = 0; t < nt; ++t) {
    const int cur = t & 1;
    if (t + 1 < nt) stage(cur ^ 1, t + 1);
    const char* as = (const char*)As[cur];
    const char* bs = (const char*)Bs[cur];
    bf16x8 af[4], bfv[4];
#pragma unroll
    for (int m = 0; m < 4; ++m)
      af[m] = *(const bf16x8*)(as + (wr * 64 + m * 16 + r16) * 64 + g * 16);
#pragma unroll
    for (int n = 0; n < 4; ++n)
      bfv[n] = *(const bf16x8*)(bs + (wc * 64 + n * 16 + r16) * 64 + g * 16);
#pragma unroll
    for (int m = 0; m < 4; ++m)
#pragma unroll
      for (int n = 0; n < 4; ++n)
        acc[m][n] = MFMA16(af[m], bfv[n], acc[m][n]);
    __syncthreads();
  }

  const int type = bn % 3, p = bn / 3;
#pragma unroll
  for (int m = 0; m < 4; ++m) {
    const int s0 = row0 + wr * 64 + m * 16 + g * 4;
#pragma unroll
    for (int n = 0; n < 4; ++n) {
      const int d = wc * 64 + n * 16 + r16;
      if (type == 0) {
#pragma unroll
        for (int r = 0; r < 4; ++r)
          Qb[(p * S_LEN + s0 + r) * HDIM + d] = f2bf(acc[m][n][r] * QSCALE_L2E);
      } else if (type == 1) {
#pragma unroll
        for (int r = 0; r < 4; ++r)
          Kb[(p * S_LEN + s0 + r) * HDIM + d] = f2bf(acc[m][n][r]);
      } else {
        ushort4 o;
        o.x = f2bf(acc[m][n][0]); o.y = f2bf(acc[m][n][1]);
        o.z = f2bf(acc[m][n][2]); o.w = f2bf(acc[m][n][3]);
        *(ushort4*)(Vt + (p * HDIM + d) * S_LEN + s0) = o;
      }
    }
  }
}

// ---------------- partial RoPE (NeoX, first 32 dims) ----------------
__global__ __launch_bounds__(256) void rope_kernel(unsigned short* __restrict__ Qb,
                                                   unsigned short* __restrict__ Kb) {
  const int idx = blockIdx.x * 256 + threadIdx.x;
  const int p = idx >> 16, rem = idx & 65535, s = rem >> 4, d = rem & 15;
  const float invf = exp2f(-(float)d * (13.287712379549449f / 16.0f));
  const float ang = (float)s * invf;
  const float c = cosf(ang), sn = sinf(ang);
  const int base = (p * S_LEN + s) * HDIM;
  {
    float x = bf2f(Qb[base + d]), y = bf2f(Qb[base + d + 16]);
    Qb[base + d]      = f2bf(x * c - y * sn);
    Qb[base + d + 16] = f2bf(y * c + x * sn);
  }
  {
    float x = bf2f(Kb[base + d]), y = bf2f(Kb[base + d + 16]);
    Kb[base + d]      = f2bf(x * c - y * sn);
    Kb[base + d + 16] = f2bf(y * c + x * sn);
  }
}

// ---------------- causal flash attention, swapped-QK 32x32 in-register softmax ----
// grid (16, 16): y = head; block handles q-tiles qt=x and 31-x (128 rows each),
// 4 waves x 32 q-rows; KVBLK=64; lane owns one q column (col=lane&31),
// partner lane l^32 owns same q -> softmax = local tree + one shfl_xor(32).
__global__ __launch_bounds__(256, 1) void attn_kernel(
    const unsigned short* __restrict__ Qb, const unsigned short* __restrict__ Kb,
    const unsigned short* __restrict__ Vt, unsigned short* __restrict__ Ctx) {
  __shared__ __align__(16) unsigned char sm[65536];  // K 2x16K | Vt 2x16K
  unsigned char* const Kl0 = sm;
  unsigned char* const Vl0 = sm + 32768;
  const int p = blockIdx.y;
  const int tid = threadIdx.x, wid = tid >> 6, lane = tid & 63;
  const int l31 = lane & 31, hi = lane >> 5;
  const int xr = (l31 & 7) << 4;

  auto stageKV = [&](int buf, int t) {
    const unsigned short* kb = Kb + (p * S_LEN + t * 64) * HDIM;
    const unsigned short* vb = Vt + p * HDIM * S_LEN + t * 64;
#pragma unroll
    for (int c = 0; c < 4; ++c) {
      const int chunk = c * 256 + tid;
      const int byteoff = chunk * 16;
      {  // K tile [64][128], 16 chunks/row, swizzled source
        const int j = byteoff >> 8, cb = (byteoff >> 4) & 15;
        gld16(kb + j * HDIM + (cb ^ (j & 7)) * 8, Kl0 + buf * 16384 + chunk * 16);
      }
      {  // Vt tile [128][64], 8 chunks/row
        const int dd = byteoff >> 7, cb = (byteoff >> 4) & 7;
        gld16(vb + dd * S_LEN + (cb ^ (dd & 7)) * 8, Vl0 + buf * 16384 + chunk * 16);
      }
    }
  };

  for (int sel = 0; sel < 2; ++sel) {
    const int qt = sel ? 31 - (int)blockIdx.x : (int)blockIdx.x;
    const int q0w = qt * 128 + wid * 32;
    const int qg = q0w + l31;
    const int nt = 2 * (qt + 1);

    bf16x8 qf[8];
    {
      const unsigned short* qp_ = Qb + (p * S_LEN + qg) * HDIM + hi * 8;
#pragma unroll
      for (int dd = 0; dd < 8; ++dd) qf[dd] = *(const bf16x8*)(qp_ + dd * 16);
    }
    f32x16 acc[4] = {};
    float m_s = -1e30f, l_s = 0.f;

    stageKV(0, 0);
    __syncthreads();
    for (int t = 0; t < nt; ++t) {
      const int cur = t & 1;
      if (t + 1 < nt) stageKV(cur ^ 1, t + 1);
      const unsigned char* kl = Kl0 + cur * 16384;
      const unsigned char* vl = Vl0 + cur * 16384;

      // S^T[kv][q] = K . Q^T : lane holds 32 kv values for q = l31 (per s32 half)
      f32x16 sv0 = {}, sv1 = {};
#pragma unroll
      for (int dd = 0; dd < 8; ++dd) {
        bf16x8 k0 = *(const bf16x8*)(kl + l31 * 256 + (((dd * 2 + hi) << 4) ^ xr));
        bf16x8 k1 = *(const bf16x8*)(kl + (32 + l31) * 256 + (((dd * 2 + hi) << 4) ^ xr));
        sv0 = MFMA32(k0, qf[dd], sv0);
        sv1 = MFMA32(k1, qf[dd], sv1);
      }
      // causal mask (only near-diagonal tiles)
      if (t * 64 + 63 > q0w) {
#pragma unroll
        for (int r = 0; r < 16; ++r) {
          const int kv0 = t * 64 + ((r & 3) + 8 * (r >> 2)) + 4 * hi;
          if (kv0 > qg) sv0[r] = -1e30f;
          if (kv0 + 32 > qg) sv1[r] = -1e30f;
        }
      }
      // row max: local tree + partner exchange
      float mx[16];
#pragma unroll
      for (int r = 0; r < 16; ++r) mx[r] = fmaxf(sv0[r], sv1[r]);
#pragma unroll
      for (int r = 0; r < 8; ++r) mx[r] = fmaxf(mx[r], mx[r + 8]);
#pragma unroll
      for (int r = 0; r < 4; ++r) mx[r] = fmaxf(mx[r], mx[r + 4]);
      mx[0] = fmaxf(fmaxf(mx[0], mx[2]), fmaxf(mx[1], mx[3]));
      const float pm = fmaxf(mx[0], __shfl_xor(mx[0], 32, 64));
      // defer-max rescale (THR = 8 nats = 11.5 in log2 domain)
      if (__any(pm > m_s + 11.5f)) {
        const float mn = fmaxf(m_s, pm);
        const float scl = exp2f(m_s - mn);
#pragma unroll
        for (int d32 = 0; d32 < 4; ++d32)
#pragma unroll
          for (int r = 0; r < 16; ++r) acc[d32][r] *= scl;
        l_s *= scl;
        m_s = mn;
      }
      // P = exp2(S - m)  (Q pre-scaled by 1/sqrt(d)*log2e)
#pragma unroll
      for (int r = 0; r < 16; ++r) {
        sv0[r] = exp2f(sv0[r] - m_s);
        sv1[r] = exp2f(sv1[r] - m_s);
      }
      {
        float s_[8];
#pragma unroll
        for (int r = 0; r < 8; ++r) s_[r] = (sv0[r] + sv0[r + 8]) + (sv1[r] + sv1[r + 8]);
#pragma unroll
        for (int r = 0; r < 4; ++r) s_[r] += s_[r + 4];
        const float rs = (s_[0] + s_[1]) + (s_[2] + s_[3]);
        l_s += rs + __shfl_xor(rs, 32, 64);
      }
      // pack P^T into PV B-fragments: own pairs + partner pairs via shfl_xor(32)
      bf16x8 pf[4];
#define PACKB(B, SV, base)                                                        \
      {                                                                           \
        unsigned X0 = cvtpk_bf16(SV[base + 0], SV[base + 1]);                     \
        unsigned X1 = cvtpk_bf16(SV[base + 2], SV[base + 3]);                     \
        unsigned Y0 = cvtpk_bf16(SV[base + 4], SV[base + 5]);                     \
        unsigned Y1 = cvtpk_bf16(SV[base + 6], SV[base + 7]);                     \
        unsigned sX0 = __shfl_xor(X0, 32, 64), sX1 = __shfl_xor(X1, 32, 64);      \
        unsigned sY0 = __shfl_xor(Y0, 32, 64), sY1 = __shfl_xor(Y1, 32, 64);      \
        u32x4 pw;                                                                 \
        pw.x = hi ? sY0 : X0; pw.y = hi ? sY1 : X1;                               \
        pw.z = hi ? Y0 : sX0; pw.w = hi ? Y1 : sX1;                               \
        pf[B] = __builtin_bit_cast(bf16x8, pw);                                   \
      }
      PACKB(0, sv0, 0)
      PACKB(1, sv0, 8)
      PACKB(2, sv1, 0)
      PACKB(3, sv1, 8)
#undef PACKB
      // O^T[d][q] += V^T . P^T
#pragma unroll
      for (int d32 = 0; d32 < 4; ++d32) {
#pragma unroll
        for (int b = 0; b < 4; ++b) {
          bf16x8 vf = *(const bf16x8*)(vl + (d32 * 32 + l31) * 128 + (((b * 2 + hi) << 4) ^ xr));
          acc[d32] = MFMA32(vf, pf[b], acc[d32]);
        }
      }
      __syncthreads();
    }
    // epilogue
    const float inv = 1.0f / l_s;
    unsigned short* cbase = Ctx + qg * HID + p * HDIM;
#pragma unroll
    for (int d32 = 0; d32 < 4; ++d32)
#pragma unroll
      for (int r = 0; r < 16; ++r) {
        const int d = d32 * 32 + ((r & 3) + 8 * (r >> 2)) + 4 * hi;
        cbase[d] = f2bf(acc[d32][r] * inv);
      }
  }
}

// ---------------- dense GEMM: out[4096,2048] = ctx . wdense^T + bias (f32 out) ----------------
__global__ __launch_bounds__(256, 3) void gemm_dense_kernel(
    const unsigned short* __restrict__ A, const unsigned short* __restrict__ B,
    const float* __restrict__ bias, float* __restrict__ out) {
  __shared__ __align__(16) unsigned short As[2][128 * 32];
  __shared__ __align__(16) unsigned short Bs[2][128 * 32];
  const int K = HID;
  const int bid = ((int)blockIdx.x % 8) * 64 + (int)blockIdx.x / 8;
  const int bm = bid / 16, bn = bid % 16;
  const int row0 = bm * 128, col0 = bn * 128;
  const int tid = threadIdx.x;
  const int wid = tid >> 6, lane = tid & 63;
  const int g = lane >> 4, r16 = lane & 15;
  const int wr = wid >> 1, wc = wid & 1;

  f32x4 acc[4][4] = {};

  int srow[2], scol[2];
#pragma unroll
  for (int c = 0; c < 2; ++c) {
    int byteoff = (wid * 2 + c) * 1024 + lane * 16;
    srow[c] = byteoff >> 6;
    scol[c] = (byteoff & 63) >> 1;
  }
  auto stage = [&](int buf, int t) {
    const int k0 = t * 32;
#pragma unroll
    for (int c = 0; c < 2; ++c) {
      gld16(A + (row0 + srow[c]) * K + k0 + scol[c], &As[buf][(wid * 2 + c) * 512]);
      gld16(B + (col0 + srow[c]) * K + k0 + scol[c], &Bs[buf][(wid * 2 + c) * 512]);
    }
  };

  const int nt = K / 32;
  stage(0, 0);
  __syncthreads();
  for (int t = 0; t < nt; ++t) {
    const int cur = t & 1;
    if (t + 1 < nt) stage(cur ^ 1, t + 1);
    const char* as = (const char*)As[cur];
    const char* bs = (const char*)Bs[cur];
    bf16x8 af[4], bfv[4];
#pragma unroll
    for (int m = 0; m < 4; ++m)
      af[m] = *(const bf16x8*)(as + (wr * 64 + m * 16 + r16) * 64 + g * 16);
#pragma unroll
    for (int n = 0; n < 4; ++n)
      bfv[n] = *(const bf16x8*)(bs + (wc * 64 + n * 16 + r16) * 64 + g * 16);
#pragma unroll
    for (int m = 0; m < 4; ++m)
#pragma unroll
      for (int n = 0; n < 4; ++n)
        acc[m][n] = MFMA16(af[m], bfv[n], acc[m][n]);
    __syncthreads();
  }

#pragma unroll
  for (int m = 0; m < 4; ++m) {
    const int s0 = row0 + wr * 64 + m * 16 + g * 4;
#pragma unroll
    for (int n = 0; n < 4; ++n) {
      const int col = col0 + wc * 64 + n * 16 + r16;
      const float bv = bias[col];
#pragma unroll
      for (int r = 0; r < 4; ++r)
        out[(s0 + r) * HID + col] = acc[m][n][r] + bv;
    }
  }
}

extern "C" void kernel_launch(void* const* d_in, const int* in_sizes, int n_in,
                              void* d_out, int out_size, void* d_ws, size_t ws_size,
                              hipStream_t stream) {
  (void)in_sizes; (void)n_in; (void)out_size; (void)ws_size;
  const float* hidden = (const float*)d_in[0];
  const float* wqkv   = (const float*)d_in[2];
  const float* wdense = (const float*)d_in[3];
  const float* bdense = (const float*)d_in[4];
  float* out = (float*)d_out;

  char* ws = (char*)d_ws;
  unsigned short* hiddenB = (unsigned short*)(ws);
  unsigned short* wqkvB   = (unsigned short*)(ws + 16777216);
  unsigned short* wdenseB = (unsigned short*)(ws + 41943040);
  unsigned short* Qb      = (unsigned short*)(ws + 50331648);
  unsigned short* Kb      = (unsigned short*)(ws + 67108864);
  unsigned short* Vt      = (unsigned short*)(ws + 83886080);
  unsigned short* ctxB    = (unsigned short*)(ws + 100663296);

  cvt_kernel<<<8192, 256, 0, stream>>>(hidden, hiddenB, 8388608);
  cvt_kernel<<<12288, 256, 0, stream>>>(wqkv, wqkvB, 12582912);
  cvt_kernel<<<4096, 256, 0, stream>>>(wdense, wdenseB, 4194304);
  gemm_qkv_kernel<<<1536, 256, 0, stream>>>(hiddenB, wqkvB, Qb, Kb, Vt);
  rope_kernel<<<4096, 256, 0, stream>>>(Qb, Kb);
  attn_kernel<<<dim3(16, 16), 256, 0, stream>>>(Qb, Kb, Vt, ctxB);
  gemm_dense_kernel<<<512, 256, 0, stream>>>(ctxB, wdenseB, bdense, out);
}

// Round 3
// 347.578 us; speedup vs baseline: 1.1523x; 1.0520x over previous
//
#include <hip/hip_runtime.h>

#define S_LEN 4096
#define HID   2048
#define NHEAD 16
#define HDIM  128
// 1/sqrt(128) * log2(e): Q pre-scale so softmax can use exp2 directly
#define QSCALE_L2E 0.12751664352f

typedef float  f32x4  __attribute__((ext_vector_type(4)));
typedef float  f32x16 __attribute__((ext_vector_type(16)));
typedef __bf16 bf16x8 __attribute__((ext_vector_type(8)));
typedef unsigned u32x4 __attribute__((ext_vector_type(4)));

#define MFMA16(a, b, c) __builtin_amdgcn_mfma_f32_16x16x32_bf16((a), (b), (c), 0, 0, 0)
#define MFMA32(a, b, c) __builtin_amdgcn_mfma_f32_32x32x16_bf16((a), (b), (c), 0, 0, 0)

__device__ __forceinline__ void gld16(const void* g, void* l) {
  __builtin_amdgcn_global_load_lds(
      (const __attribute__((address_space(1))) void*)(unsigned long long)(g),
      (__attribute__((address_space(3))) void*)(unsigned long long)(l),
      16, 0, 0);
}

__device__ __forceinline__ unsigned short f2bf(float f) {
  union { float f; unsigned u; } v; v.f = f;
  unsigned r = v.u + 0x7FFFu + ((v.u >> 16) & 1u);
  return (unsigned short)(r >> 16);
}
__device__ __forceinline__ float bf2f(unsigned short h) {
  union { unsigned u; float f; } v; v.u = ((unsigned)h) << 16;
  return v.f;
}
__device__ __forceinline__ unsigned cvtpk_bf16(float a, float b) {
  unsigned r;
  asm("v_cvt_pk_bf16_f32 %0, %1, %2" : "=v"(r) : "v"(a), "v"(b));
  return r;
}

// ---------------- f32 -> bf16 conversion ----------------
__global__ __launch_bounds__(256) void cvt_kernel(const float* __restrict__ src,
                                                  unsigned short* __restrict__ dst, int n) {
  int i = (blockIdx.x * 256 + threadIdx.x) * 4;
  if (i >= n) return;
  const float4 v = *(const float4*)(src + i);
  ushort4 o;
  o.x = f2bf(v.x); o.y = f2bf(v.y); o.z = f2bf(v.z); o.w = f2bf(v.w);
  *(ushort4*)(dst + i) = o;
}

// ---------------- QKV GEMM: C[4096,6144] = hidden[4096,2048] . wqkv[6144,2048]^T
__global__ __launch_bounds__(256, 3) void gemm_qkv_kernel(
    const unsigned short* __restrict__ A, const unsigned short* __restrict__ B,
    unsigned short* __restrict__ Qb, unsigned short* __restrict__ Kb,
    unsigned short* __restrict__ Vt) {
  __shared__ __align__(16) unsigned short As[2][128 * 32];
  __shared__ __align__(16) unsigned short Bs[2][128 * 32];
  const int K = HID;
  const int bid = ((int)blockIdx.x % 8) * 192 + (int)blockIdx.x / 8;
  const int bm = bid / 48, bn = bid % 48;
  const int row0 = bm * 128, col0 = bn * 128;
  const int tid = threadIdx.x;
  const int wid = tid >> 6, lane = tid & 63;
  const int g = lane >> 4, r16 = lane & 15;
  const int wr = wid >> 1, wc = wid & 1;

  f32x4 acc[4][4] = {};

  int srow[2], scol[2];
#pragma unroll
  for (int c = 0; c < 2; ++c) {
    int byteoff = (wid * 2 + c) * 1024 + lane * 16;
    srow[c] = byteoff >> 6;
    scol[c] = (byteoff & 63) >> 1;
  }

  auto stage = [&](int buf, int t) {
    const int k0 = t * 32;
#pragma unroll
    for (int c = 0; c < 2; ++c) {
      gld16(A + (row0 + srow[c]) * K + k0 + scol[c], &As[buf][(wid * 2 + c) * 512]);
      gld16(B + (col0 + srow[c]) * K + k0 + scol[c], &Bs[buf][(wid * 2 + c) * 512]);
    }
  };

  const int nt = K / 32;
  stage(0, 0);
  __syncthreads();
  for (int t = 0; t < nt; ++t) {
    const int cur = t & 1;
    if (t + 1 < nt) stage(cur ^ 1, t + 1);
    const char* as = (const char*)As[cur];
    const char* bs = (const char*)Bs[cur];
    bf16x8 af[4], bfv[4];
#pragma unroll
    for (int m = 0; m < 4; ++m)
      af[m] = *(const bf16x8*)(as + (wr * 64 + m * 16 + r16) * 64 + g * 16);
#pragma unroll
    for (int n = 0; n < 4; ++n)
      bfv[n] = *(const bf16x8*)(bs + (wc * 64 + n * 16 + r16) * 64 + g * 16);
#pragma unroll
    for (int m = 0; m < 4; ++m)
#pragma unroll
      for (int n = 0; n < 4; ++n)
        acc[m][n] = MFMA16(af[m], bfv[n], acc[m][n]);
    __syncthreads();
  }

  const int type = bn % 3, p = bn / 3;
#pragma unroll
  for (int m = 0; m < 4; ++m) {
    const int s0 = row0 + wr * 64 + m * 16 + g * 4;
#pragma unroll
    for (int n = 0; n < 4; ++n) {
      const int d = wc * 64 + n * 16 + r16;
      if (type == 0) {
#pragma unroll
        for (int r = 0; r < 4; ++r)
          Qb[(p * S_LEN + s0 + r) * HDIM + d] = f2bf(acc[m][n][r] * QSCALE_L2E);
      } else if (type == 1) {
#pragma unroll
        for (int r = 0; r < 4; ++r)
          Kb[(p * S_LEN + s0 + r) * HDIM + d] = f2bf(acc[m][n][r]);
      } else {
        ushort4 o;
        o.x = f2bf(acc[m][n][0]); o.y = f2bf(acc[m][n][1]);
        o.z = f2bf(acc[m][n][2]); o.w = f2bf(acc[m][n][3]);
        *(ushort4*)(Vt + (p * HDIM + d) * S_LEN + s0) = o;
      }
    }
  }
}

// ---------------- partial RoPE (NeoX, first 32 dims) ----------------
__global__ __launch_bounds__(256) void rope_kernel(unsigned short* __restrict__ Qb,
                                                   unsigned short* __restrict__ Kb) {
  const int idx = blockIdx.x * 256 + threadIdx.x;
  const int p = idx >> 16, rem = idx & 65535, s = rem >> 4, d = rem & 15;
  const float invf = exp2f(-(float)d * (13.287712379549449f / 16.0f));
  const float ang = (float)s * invf;
  const float c = cosf(ang), sn = sinf(ang);
  const int base = (p * S_LEN + s) * HDIM;
  {
    float x = bf2f(Qb[base + d]), y = bf2f(Qb[base + d + 16]);
    Qb[base + d]      = f2bf(x * c - y * sn);
    Qb[base + d + 16] = f2bf(y * c + x * sn);
  }
  {
    float x = bf2f(Kb[base + d]), y = bf2f(Kb[base + d + 16]);
    Kb[base + d]      = f2bf(x * c - y * sn);
    Kb[base + d + 16] = f2bf(y * c + x * sn);
  }
}

// ---------------- causal flash attention, swapped-QK 32x32 in-register softmax ----
// grid 512: head = b&15; qt = b<256 ? b>>4 : 47-(b>>4)  (blocks c and c+256 land on
// the same CU round-robin and their qt sum to 31 -> uniform per-CU work; each XCD
// sees 2 heads -> 4MB KV = L2 size). 4 waves x 32 q-rows, KVBLK=64, 2 blocks/CU.
__global__ __launch_bounds__(256, 2) void attn_kernel(
    const unsigned short* __restrict__ Qb, const unsigned short* __restrict__ Kb,
    const unsigned short* __restrict__ Vt, unsigned short* __restrict__ Ctx) {
  __shared__ __align__(16) unsigned char sm[65536];  // K 2x16K | Vt 2x16K
  unsigned char* const Kl0 = sm;
  unsigned char* const Vl0 = sm + 32768;
  const int b = (int)blockIdx.x;
  const int p = b & 15;
  const int qt = (b < 256) ? (b >> 4) : 47 - (b >> 4);
  const int tid = threadIdx.x, wid = tid >> 6, lane = tid & 63;
  const int l31 = lane & 31, hi = lane >> 5;
  const int xr = (l31 & 7) << 4;

  auto stageKV = [&](int buf, int t) {
    const unsigned short* kb = Kb + (p * S_LEN + t * 64) * HDIM;
    const unsigned short* vb = Vt + p * HDIM * S_LEN + t * 64;
#pragma unroll
    for (int c = 0; c < 4; ++c) {
      const int chunk = c * 256 + tid;
      const int byteoff = chunk * 16;
      {  // K tile [64][128], 16 chunks/row, swizzled source
        const int j = byteoff >> 8, cb = (byteoff >> 4) & 15;
        gld16(kb + j * HDIM + (cb ^ (j & 7)) * 8, Kl0 + buf * 16384 + chunk * 16);
      }
      {  // Vt tile [128][64], 8 chunks/row
        const int dd = byteoff >> 7, cb = (byteoff >> 4) & 7;
        gld16(vb + dd * S_LEN + (cb ^ (dd & 7)) * 8, Vl0 + buf * 16384 + chunk * 16);
      }
    }
  };

  const int q0w = qt * 128 + wid * 32;
  const int qg = q0w + l31;
  const int nt = 2 * (qt + 1);

  stageKV(0, 0);
  bf16x8 qf[8];
  {
    const unsigned short* qp_ = Qb + (p * S_LEN + qg) * HDIM + hi * 8;
#pragma unroll
    for (int dd = 0; dd < 8; ++dd) qf[dd] = *(const bf16x8*)(qp_ + dd * 16);
  }
  f32x16 acc[4] = {};
  float m_s = -1e30f, l_s = 0.f;

  __syncthreads();
  for (int t = 0; t < nt; ++t) {
    const int cur = t & 1;
    if (t + 1 < nt) stageKV(cur ^ 1, t + 1);
    const unsigned char* kl = Kl0 + cur * 16384;
    const unsigned char* vl = Vl0 + cur * 16384;

    // S^T[kv][q] = K . Q^T : lane holds 32 kv values for q = l31 (per s32 half)
    f32x16 sv0 = {}, sv1 = {};
#pragma unroll
    for (int dd = 0; dd < 8; ++dd) {
      bf16x8 k0 = *(const bf16x8*)(kl + l31 * 256 + (((dd * 2 + hi) << 4) ^ xr));
      bf16x8 k1 = *(const bf16x8*)(kl + (32 + l31) * 256 + (((dd * 2 + hi) << 4) ^ xr));
      sv0 = MFMA32(k0, qf[dd], sv0);
      sv1 = MFMA32(k1, qf[dd], sv1);
    }
    // causal mask (only near-diagonal tiles)
    if (t * 64 + 63 > q0w) {
#pragma unroll
      for (int r = 0; r < 16; ++r) {
        const int kv0 = t * 64 + ((r & 3) + 8 * (r >> 2)) + 4 * hi;
        if (kv0 > qg) sv0[r] = -1e30f;
        if (kv0 + 32 > qg) sv1[r] = -1e30f;
      }
    }
    // row max: local tree + partner exchange
    float mx[16];
#pragma unroll
    for (int r = 0; r < 16; ++r) mx[r] = fmaxf(sv0[r], sv1[r]);
#pragma unroll
    for (int r = 0; r < 8; ++r) mx[r] = fmaxf(mx[r], mx[r + 8]);
#pragma unroll
    for (int r = 0; r < 4; ++r) mx[r] = fmaxf(mx[r], mx[r + 4]);
    mx[0] = fmaxf(fmaxf(mx[0], mx[2]), fmaxf(mx[1], mx[3]));
    const float pm = fmaxf(mx[0], __shfl_xor(mx[0], 32, 64));
    // defer-max rescale (THR = 8 nats = 11.5 in log2 domain)
    if (__any(pm > m_s + 11.5f)) {
      const float mn = fmaxf(m_s, pm);
      const float scl = exp2f(m_s - mn);
#pragma unroll
      for (int d32 = 0; d32 < 4; ++d32)
#pragma unroll
        for (int r = 0; r < 16; ++r) acc[d32][r] *= scl;
      l_s *= scl;
      m_s = mn;
    }
    // P = exp2(S - m)  (Q pre-scaled by 1/sqrt(d)*log2e)
#pragma unroll
    for (int r = 0; r < 16; ++r) {
      sv0[r] = exp2f(sv0[r] - m_s);
      sv1[r] = exp2f(sv1[r] - m_s);
    }
    {
      float s_[8];
#pragma unroll
      for (int r = 0; r < 8; ++r) s_[r] = (sv0[r] + sv0[r + 8]) + (sv1[r] + sv1[r + 8]);
#pragma unroll
      for (int r = 0; r < 4; ++r) s_[r] += s_[r + 4];
      const float rs = (s_[0] + s_[1]) + (s_[2] + s_[3]);
      l_s += rs + __shfl_xor(rs, 32, 64);
    }
    // pack P^T into PV B-fragments: own pairs + partner pairs via shfl_xor(32)
    bf16x8 pf[4];
#define PACKB(B, SV, base)                                                        \
    {                                                                             \
      unsigned X0 = cvtpk_bf16(SV[base + 0], SV[base + 1]);                       \
      unsigned X1 = cvtpk_bf16(SV[base + 2], SV[base + 3]);                       \
      unsigned Y0 = cvtpk_bf16(SV[base + 4], SV[base + 5]);                       \
      unsigned Y1 = cvtpk_bf16(SV[base + 6], SV[base + 7]);                       \
      unsigned sX0 = __shfl_xor(X0, 32, 64), sX1 = __shfl_xor(X1, 32, 64);        \
      unsigned sY0 = __shfl_xor(Y0, 32, 64), sY1 = __shfl_xor(Y1, 32, 64);        \
      u32x4 pw;                                                                   \
      pw.x = hi ? sY0 : X0; pw.y = hi ? sY1 : X1;                                 \
      pw.z = hi ? Y0 : sX0; pw.w = hi ? Y1 : sX1;                                 \
      pf[B] = __builtin_bit_cast(bf16x8, pw);                                     \
    }
    PACKB(0, sv0, 0)
    PACKB(1, sv0, 8)
    PACKB(2, sv1, 0)
    PACKB(3, sv1, 8)
#undef PACKB
    // O^T[d][q] += V^T . P^T
#pragma unroll
    for (int d32 = 0; d32 < 4; ++d32) {
#pragma unroll
      for (int bb = 0; bb < 4; ++bb) {
        bf16x8 vf = *(const bf16x8*)(vl + (d32 * 32 + l31) * 128 + (((bb * 2 + hi) << 4) ^ xr));
        acc[d32] = MFMA32(vf, pf[bb], acc[d32]);
      }
    }
    __syncthreads();
  }
  // epilogue
  const float inv = 1.0f / l_s;
  unsigned short* cbase = Ctx + qg * HID + p * HDIM;
#pragma unroll
  for (int d32 = 0; d32 < 4; ++d32)
#pragma unroll
    for (int r = 0; r < 16; ++r) {
      const int d = d32 * 32 + ((r & 3) + 8 * (r >> 2)) + 4 * hi;
      cbase[d] = f2bf(acc[d32][r] * inv);
    }
}

// ---------------- dense GEMM: out[4096,2048] = ctx . wdense^T + bias (f32 out) ----------------
__global__ __launch_bounds__(256, 3) void gemm_dense_kernel(
    const unsigned short* __restrict__ A, const unsigned short* __restrict__ B,
    const float* __restrict__ bias, float* __restrict__ out) {
  __shared__ __align__(16) unsigned short As[2][128 * 32];
  __shared__ __align__(16) unsigned short Bs[2][128 * 32];
  const int K = HID;
  const int bid = ((int)blockIdx.x % 8) * 64 + (int)blockIdx.x / 8;
  const int bm = bid / 16, bn = bid % 16;
  const int row0 = bm * 128, col0 = bn * 128;
  const int tid = threadIdx.x;
  const int wid = tid >> 6, lane = tid & 63;
  const int g = lane >> 4, r16 = lane & 15;
  const int wr = wid >> 1, wc = wid & 1;

  f32x4 acc[4][4] = {};

  int srow[2], scol[2];
#pragma unroll
  for (int c = 0; c < 2; ++c) {
    int byteoff = (wid * 2 + c) * 1024 + lane * 16;
    srow[c] = byteoff >> 6;
    scol[c] = (byteoff & 63) >> 1;
  }
  auto stage = [&](int buf, int t) {
    const int k0 = t * 32;
#pragma unroll
    for (int c = 0; c < 2; ++c) {
      gld16(A + (row0 + srow[c]) * K + k0 + scol[c], &As[buf][(wid * 2 + c) * 512]);
      gld16(B + (col0 + srow[c]) * K + k0 + scol[c], &Bs[buf][(wid * 2 + c) * 512]);
    }
  };

  const int nt = K / 32;
  stage(0, 0);
  __syncthreads();
  for (int t = 0; t < nt; ++t) {
    const int cur = t & 1;
    if (t + 1 < nt) stage(cur ^ 1, t + 1);
    const char* as = (const char*)As[cur];
    const char* bs = (const char*)Bs[cur];
    bf16x8 af[4], bfv[4];
#pragma unroll
    for (int m = 0; m < 4; ++m)
      af[m] = *(const bf16x8*)(as + (wr * 64 + m * 16 + r16) * 64 + g * 16);
#pragma unroll
    for (int n = 0; n < 4; ++n)
      bfv[n] = *(const bf16x8*)(bs + (wc * 64 + n * 16 + r16) * 64 + g * 16);
#pragma unroll
    for (int m = 0; m < 4; ++m)
#pragma unroll
      for (int n = 0; n < 4; ++n)
        acc[m][n] = MFMA16(af[m], bfv[n], acc[m][n]);
    __syncthreads();
  }

#pragma unroll
  for (int m = 0; m < 4; ++m) {
    const int s0 = row0 + wr * 64 + m * 16 + g * 4;
#pragma unroll
    for (int n = 0; n < 4; ++n) {
      const int col = col0 + wc * 64 + n * 16 + r16;
      const float bv = bias[col];
#pragma unroll
      for (int r = 0; r < 4; ++r)
        out[(s0 + r) * HID + col] = acc[m][n][r] + bv;
    }
  }
}

extern "C" void kernel_launch(void* const* d_in, const int* in_sizes, int n_in,
                              void* d_out, int out_size, void* d_ws, size_t ws_size,
                              hipStream_t stream) {
  (void)in_sizes; (void)n_in; (void)out_size; (void)ws_size;
  const float* hidden = (const float*)d_in[0];
  const float* wqkv   = (const float*)d_in[2];
  const float* wdense = (const float*)d_in[3];
  const float* bdense = (const float*)d_in[4];
  float* out = (float*)d_out;

  char* ws = (char*)d_ws;
  unsigned short* hiddenB = (unsigned short*)(ws);
  unsigned short* wqkvB   = (unsigned short*)(ws + 16777216);
  unsigned short* wdenseB = (unsigned short*)(ws + 41943040);
  unsigned short* Qb      = (unsigned short*)(ws + 50331648);
  unsigned short* Kb      = (unsigned short*)(ws + 67108864);
  unsigned short* Vt      = (unsigned short*)(ws + 83886080);
  unsigned short* ctxB    = (unsigned short*)(ws + 100663296);

  cvt_kernel<<<8192, 256, 0, stream>>>(hidden, hiddenB, 8388608);
  cvt_kernel<<<12288, 256, 0, stream>>>(wqkv, wqkvB, 12582912);
  cvt_kernel<<<4096, 256, 0, stream>>>(wdense, wdenseB, 4194304);
  gemm_qkv_kernel<<<1536, 256, 0, stream>>>(hiddenB, wqkvB, Qb, Kb, Vt);
  rope_kernel<<<4096, 256, 0, stream>>>(Qb, Kb);
  attn_kernel<<<512, 256, 0, stream>>>(Qb, Kb, Vt, ctxB);
  gemm_dense_kernel<<<512, 256, 0, stream>>>(ctxB, wdenseB, bdense, out);
}

// Round 4
// 339.693 us; speedup vs baseline: 1.1791x; 1.0232x over previous
//
#include <hip/hip_runtime.h>

#define S_LEN 4096
#define HID   2048
#define NHEAD 16
#define HDIM  128
// 1/sqrt(128) * log2(e): Q pre-scale so softmax can use exp2 directly
#define QSCALE_L2E 0.12751664352f

typedef float  f32x4  __attribute__((ext_vector_type(4)));
typedef float  f32x16 __attribute__((ext_vector_type(16)));
typedef __bf16 bf16x8 __attribute__((ext_vector_type(8)));
typedef unsigned u32x4 __attribute__((ext_vector_type(4)));
typedef unsigned u32x2 __attribute__((ext_vector_type(2)));

#define MFMA16(a, b, c) __builtin_amdgcn_mfma_f32_16x16x32_bf16((a), (b), (c), 0, 0, 0)
#define MFMA32(a, b, c) __builtin_amdgcn_mfma_f32_32x32x16_bf16((a), (b), (c), 0, 0, 0)

__device__ __forceinline__ void gld16(const void* g, void* l) {
  __builtin_amdgcn_global_load_lds(
      (const __attribute__((address_space(1))) void*)(unsigned long long)(g),
      (__attribute__((address_space(3))) void*)(unsigned long long)(l),
      16, 0, 0);
}

__device__ __forceinline__ unsigned short f2bf(float f) {
  union { float f; unsigned u; } v; v.f = f;
  unsigned r = v.u + 0x7FFFu + ((v.u >> 16) & 1u);
  return (unsigned short)(r >> 16);
}
__device__ __forceinline__ float bf2f(unsigned short h) {
  union { unsigned u; float f; } v; v.u = ((unsigned)h) << 16;
  return v.f;
}
__device__ __forceinline__ unsigned cvtpk_bf16(float a, float b) {
  unsigned r;
  asm("v_cvt_pk_bf16_f32 %0, %1, %2" : "=v"(r) : "v"(a), "v"(b));
  return r;
}
// lane l<32 / l>=32 exchange: ret[0] = {a.lo || b.lo}, ret[1] = {a.hi || b.hi}
__device__ __forceinline__ u32x2 pls(unsigned a, unsigned b) {
  return __builtin_amdgcn_permlane32_swap(a, b, false, false);
}
__device__ __forceinline__ float asf(unsigned u) { return __builtin_bit_cast(float, u); }
__device__ __forceinline__ unsigned asu(float f) { return __builtin_bit_cast(unsigned, f); }

// ---------------- f32 -> bf16 conversion ----------------
__global__ __launch_bounds__(256) void cvt_kernel(const float* __restrict__ src,
                                                  unsigned short* __restrict__ dst, int n) {
  int i = (blockIdx.x * 256 + threadIdx.x) * 4;
  if (i >= n) return;
  const float4 v = *(const float4*)(src + i);
  ushort4 o;
  o.x = f2bf(v.x); o.y = f2bf(v.y); o.z = f2bf(v.z); o.w = f2bf(v.w);
  *(ushort4*)(dst + i) = o;
}

// ---------------- QKV GEMM: C[4096,6144] = hidden[4096,2048] . wqkv[6144,2048]^T
__global__ __launch_bounds__(256, 3) void gemm_qkv_kernel(
    const unsigned short* __restrict__ A, const unsigned short* __restrict__ B,
    unsigned short* __restrict__ Qb, unsigned short* __restrict__ Kb,
    unsigned short* __restrict__ Vt) {
  __shared__ __align__(16) unsigned short As[2][128 * 32];
  __shared__ __align__(16) unsigned short Bs[2][128 * 32];
  const int K = HID;
  const int bid = ((int)blockIdx.x % 8) * 192 + (int)blockIdx.x / 8;
  const int bm = bid / 48, bn = bid % 48;
  const int row0 = bm * 128, col0 = bn * 128;
  const int tid = threadIdx.x;
  const int wid = tid >> 6, lane = tid & 63;
  const int g = lane >> 4, r16 = lane & 15;
  const int wr = wid >> 1, wc = wid & 1;

  f32x4 acc[4][4] = {};

  int srow[2], scol[2];
#pragma unroll
  for (int c = 0; c < 2; ++c) {
    int byteoff = (wid * 2 + c) * 1024 + lane * 16;
    srow[c] = byteoff >> 6;
    scol[c] = (byteoff & 63) >> 1;
  }

  auto stage = [&](int buf, int t) {
    const int k0 = t * 32;
#pragma unroll
    for (int c = 0; c < 2; ++c) {
      gld16(A + (row0 + srow[c]) * K + k0 + scol[c], &As[buf][(wid * 2 + c) * 512]);
      gld16(B + (col0 + srow[c]) * K + k0 + scol[c], &Bs[buf][(wid * 2 + c) * 512]);
    }
  };

  const int nt = K / 32;
  stage(0, 0);
  __syncthreads();
  for (int t = 0; t < nt; ++t) {
    const int cur = t & 1;
    if (t + 1 < nt) stage(cur ^ 1, t + 1);
    const char* as = (const char*)As[cur];
    const char* bs = (const char*)Bs[cur];
    bf16x8 af[4], bfv[4];
#pragma unroll
    for (int m = 0; m < 4; ++m)
      af[m] = *(const bf16x8*)(as + (wr * 64 + m * 16 + r16) * 64 + g * 16);
#pragma unroll
    for (int n = 0; n < 4; ++n)
      bfv[n] = *(const bf16x8*)(bs + (wc * 64 + n * 16 + r16) * 64 + g * 16);
#pragma unroll
    for (int m = 0; m < 4; ++m)
#pragma unroll
      for (int n = 0; n < 4; ++n)
        acc[m][n] = MFMA16(af[m], bfv[n], acc[m][n]);
    __syncthreads();
  }

  const int type = bn % 3, p = bn / 3;
#pragma unroll
  for (int m = 0; m < 4; ++m) {
    const int s0 = row0 + wr * 64 + m * 16 + g * 4;
#pragma unroll
    for (int n = 0; n < 4; ++n) {
      const int d = wc * 64 + n * 16 + r16;
      if (type == 0) {
#pragma unroll
        for (int r = 0; r < 4; ++r)
          Qb[(p * S_LEN + s0 + r) * HDIM + d] = f2bf(acc[m][n][r] * QSCALE_L2E);
      } else if (type == 1) {
#pragma unroll
        for (int r = 0; r < 4; ++r)
          Kb[(p * S_LEN + s0 + r) * HDIM + d] = f2bf(acc[m][n][r]);
      } else {
        ushort4 o;
        o.x = f2bf(acc[m][n][0]); o.y = f2bf(acc[m][n][1]);
        o.z = f2bf(acc[m][n][2]); o.w = f2bf(acc[m][n][3]);
        *(ushort4*)(Vt + (p * HDIM + d) * S_LEN + s0) = o;
      }
    }
  }
}

// ---------------- partial RoPE (NeoX, first 32 dims) ----------------
__global__ __launch_bounds__(256) void rope_kernel(unsigned short* __restrict__ Qb,
                                                   unsigned short* __restrict__ Kb) {
  const int idx = blockIdx.x * 256 + threadIdx.x;
  const int p = idx >> 16, rem = idx & 65535, s = rem >> 4, d = rem & 15;
  const float invf = exp2f(-(float)d * (13.287712379549449f / 16.0f));
  const float ang = (float)s * invf;
  const float c = cosf(ang), sn = sinf(ang);
  const int base = (p * S_LEN + s) * HDIM;
  {
    float x = bf2f(Qb[base + d]), y = bf2f(Qb[base + d + 16]);
    Qb[base + d]      = f2bf(x * c - y * sn);
    Qb[base + d + 16] = f2bf(y * c + x * sn);
  }
  {
    float x = bf2f(Kb[base + d]), y = bf2f(Kb[base + d + 16]);
    Kb[base + d]      = f2bf(x * c - y * sn);
    Kb[base + d + 16] = f2bf(y * c + x * sn);
  }
}

// ---------------- causal flash attention, swapped-QK 32x32 in-register softmax ----
// grid 512: head = b&15; qt = b<256 ? b>>4 : 47-(b>>4); 4 waves x 32 q-rows,
// KVBLK=64, 2 blocks/CU. Cross-half (l ^ 32) exchanges via v_permlane32_swap.
__global__ __launch_bounds__(256, 2) void attn_kernel(
    const unsigned short* __restrict__ Qb, const unsigned short* __restrict__ Kb,
    const unsigned short* __restrict__ Vt, unsigned short* __restrict__ Ctx) {
  __shared__ __align__(16) unsigned char sm[65536];  // K 2x16K | Vt 2x16K
  unsigned char* const Kl0 = sm;
  unsigned char* const Vl0 = sm + 32768;
  const int b = (int)blockIdx.x;
  const int p = b & 15;
  const int qt = (b < 256) ? (b >> 4) : 47 - (b >> 4);
  const int tid = threadIdx.x, wid = tid >> 6, lane = tid & 63;
  const int l31 = lane & 31, hi = lane >> 5;
  const int xr = (l31 & 7) << 4;

  auto stageKV = [&](int buf, int t) {
    const unsigned short* kb = Kb + (p * S_LEN + t * 64) * HDIM;
    const unsigned short* vb = Vt + p * HDIM * S_LEN + t * 64;
#pragma unroll
    for (int c = 0; c < 4; ++c) {
      const int chunk = c * 256 + tid;
      const int byteoff = chunk * 16;
      {  // K tile [64][128], 16 chunks/row, swizzled source
        const int j = byteoff >> 8, cb = (byteoff >> 4) & 15;
        gld16(kb + j * HDIM + (cb ^ (j & 7)) * 8, Kl0 + buf * 16384 + chunk * 16);
      }
      {  // Vt tile [128][64], 8 chunks/row
        const int dd = byteoff >> 7, cb = (byteoff >> 4) & 7;
        gld16(vb + dd * S_LEN + (cb ^ (dd & 7)) * 8, Vl0 + buf * 16384 + chunk * 16);
      }
    }
  };

  const int q0w = qt * 128 + wid * 32;
  const int qg = q0w + l31;
  const int nt = 2 * (qt + 1);

  stageKV(0, 0);
  bf16x8 qf[8];
  {
    const unsigned short* qp_ = Qb + (p * S_LEN + qg) * HDIM + hi * 8;
#pragma unroll
    for (int dd = 0; dd < 8; ++dd) qf[dd] = *(const bf16x8*)(qp_ + dd * 16);
  }
  f32x16 acc[4] = {};
  float m_s = -1e30f, l_s = 0.f;

  __syncthreads();
  for (int t = 0; t < nt; ++t) {
    const int cur = t & 1;
    if (t + 1 < nt) stageKV(cur ^ 1, t + 1);
    const unsigned char* kl = Kl0 + cur * 16384;
    const unsigned char* vl = Vl0 + cur * 16384;

    // S^T[kv][q] = K . Q^T : lane holds 32 kv values for q = l31 (per s32 half)
    f32x16 sv0 = {}, sv1 = {};
    __builtin_amdgcn_s_setprio(1);
#pragma unroll
    for (int dd = 0; dd < 8; ++dd) {
      bf16x8 k0 = *(const bf16x8*)(kl + l31 * 256 + (((dd * 2 + hi) << 4) ^ xr));
      bf16x8 k1 = *(const bf16x8*)(kl + (32 + l31) * 256 + (((dd * 2 + hi) << 4) ^ xr));
      sv0 = MFMA32(k0, qf[dd], sv0);
      sv1 = MFMA32(k1, qf[dd], sv1);
    }
    __builtin_amdgcn_s_setprio(0);
    // causal mask (only near-diagonal tiles)
    if (t * 64 + 63 > q0w) {
#pragma unroll
      for (int r = 0; r < 16; ++r) {
        const int kv0 = t * 64 + ((r & 3) + 8 * (r >> 2)) + 4 * hi;
        if (kv0 > qg) sv0[r] = -1e30f;
        if (kv0 + 32 > qg) sv1[r] = -1e30f;
      }
    }
    // row max: local tree + partner exchange (permlane32_swap, VALU)
    float mx[16];
#pragma unroll
    for (int r = 0; r < 16; ++r) mx[r] = fmaxf(sv0[r], sv1[r]);
#pragma unroll
    for (int r = 0; r < 8; ++r) mx[r] = fmaxf(mx[r], mx[r + 8]);
#pragma unroll
    for (int r = 0; r < 4; ++r) mx[r] = fmaxf(mx[r], mx[r + 4]);
    mx[0] = fmaxf(fmaxf(mx[0], mx[2]), fmaxf(mx[1], mx[3]));
    float pm;
    {
      u32x2 e = pls(asu(mx[0]), asu(mx[0]));
      pm = fmaxf(asf(e.x), asf(e.y));
    }
    // defer-max rescale (THR = 8 nats = 11.5 in log2 domain)
    if (__any(pm > m_s + 11.5f)) {
      const float mn = fmaxf(m_s, pm);
      const float scl = exp2f(m_s - mn);
#pragma unroll
      for (int d32 = 0; d32 < 4; ++d32)
#pragma unroll
        for (int r = 0; r < 16; ++r) acc[d32][r] *= scl;
      l_s *= scl;
      m_s = mn;
    }
    // P = exp2(S - m)  (Q pre-scaled by 1/sqrt(d)*log2e)
#pragma unroll
    for (int r = 0; r < 16; ++r) {
      sv0[r] = exp2f(sv0[r] - m_s);
      sv1[r] = exp2f(sv1[r] - m_s);
    }
    {
      float s_[8];
#pragma unroll
      for (int r = 0; r < 8; ++r) s_[r] = (sv0[r] + sv0[r + 8]) + (sv1[r] + sv1[r + 8]);
#pragma unroll
      for (int r = 0; r < 4; ++r) s_[r] += s_[r + 4];
      const float rs = (s_[0] + s_[1]) + (s_[2] + s_[3]);
      u32x2 e = pls(asu(rs), asu(rs));
      l_s += asf(e.x) + asf(e.y);
    }
    // pack P^T into PV B-fragments: cross-half via permlane32_swap
    bf16x8 pf[4];
#define PACKB(B, SV, base)                                                        \
    {                                                                             \
      unsigned X0 = cvtpk_bf16(SV[base + 0], SV[base + 1]);                       \
      unsigned X1 = cvtpk_bf16(SV[base + 2], SV[base + 3]);                       \
      unsigned Y0 = cvtpk_bf16(SV[base + 4], SV[base + 5]);                       \
      unsigned Y1 = cvtpk_bf16(SV[base + 6], SV[base + 7]);                       \
      u32x2 e0 = pls(X0, Y0);                                                     \
      u32x2 e1 = pls(X1, Y1);                                                     \
      u32x4 pw;                                                                   \
      pw.x = e0.x; pw.y = e1.x; pw.z = e0.y; pw.w = e1.y;                         \
      pf[B] = __builtin_bit_cast(bf16x8, pw);                                     \
    }
    PACKB(0, sv0, 0)
    PACKB(1, sv0, 8)
    PACKB(2, sv1, 0)
    PACKB(3, sv1, 8)
#undef PACKB
    // O^T[d][q] += V^T . P^T
    __builtin_amdgcn_s_setprio(1);
#pragma unroll
    for (int d32 = 0; d32 < 4; ++d32) {
#pragma unroll
      for (int bb = 0; bb < 4; ++bb) {
        bf16x8 vf = *(const bf16x8*)(vl + (d32 * 32 + l31) * 128 + (((bb * 2 + hi) << 4) ^ xr));
        acc[d32] = MFMA32(vf, pf[bb], acc[d32]);
      }
    }
    __builtin_amdgcn_s_setprio(0);
    __syncthreads();
  }
  // epilogue
  const float inv = 1.0f / l_s;
  unsigned short* cbase = Ctx + qg * HID + p * HDIM;
#pragma unroll
  for (int d32 = 0; d32 < 4; ++d32)
#pragma unroll
    for (int r = 0; r < 16; ++r) {
      const int d = d32 * 32 + ((r & 3) + 8 * (r >> 2)) + 4 * hi;
      cbase[d] = f2bf(acc[d32][r] * inv);
    }
}

// ---------------- dense GEMM: out[4096,2048] = ctx . wdense^T + bias (f32 out) ----------------
__global__ __launch_bounds__(256, 3) void gemm_dense_kernel(
    const unsigned short* __restrict__ A, const unsigned short* __restrict__ B,
    const float* __restrict__ bias, float* __restrict__ out) {
  __shared__ __align__(16) unsigned short As[2][128 * 32];
  __shared__ __align__(16) unsigned short Bs[2][128 * 32];
  const int K = HID;
  const int bid = ((int)blockIdx.x % 8) * 64 + (int)blockIdx.x / 8;
  const int bm = bid / 16, bn = bid % 16;
  const int row0 = bm * 128, col0 = bn * 128;
  const int tid = threadIdx.x;
  const int wid = tid >> 6, lane = tid & 63;
  const int g = lane >> 4, r16 = lane & 15;
  const int wr = wid >> 1, wc = wid & 1;

  f32x4 acc[4][4] = {};

  int srow[2], scol[2];
#pragma unroll
  for (int c = 0; c < 2; ++c) {
    int byteoff = (wid * 2 + c) * 1024 + lane * 16;
    srow[c] = byteoff >> 6;
    scol[c] = (byteoff & 63) >> 1;
  }
  auto stage = [&](int buf, int t) {
    const int k0 = t * 32;
#pragma unroll
    for (int c = 0; c < 2; ++c) {
      gld16(A + (row0 + srow[c]) * K + k0 + scol[c], &As[buf][(wid * 2 + c) * 512]);
      gld16(B + (col0 + srow[c]) * K + k0 + scol[c], &Bs[buf][(wid * 2 + c) * 512]);
    }
  };

  const int nt = K / 32;
  stage(0, 0);
  __syncthreads();
  for (int t = 0; t < nt; ++t) {
    const int cur = t & 1;
    if (t + 1 < nt) stage(cur ^ 1, t + 1);
    const char* as = (const char*)As[cur];
    const char* bs = (const char*)Bs[cur];
    bf16x8 af[4], bfv[4];
#pragma unroll
    for (int m = 0; m < 4; ++m)
      af[m] = *(const bf16x8*)(as + (wr * 64 + m * 16 + r16) * 64 + g * 16);
#pragma unroll
    for (int n = 0; n < 4; ++n)
      bfv[n] = *(const bf16x8*)(bs + (wc * 64 + n * 16 + r16) * 64 + g * 16);
#pragma unroll
    for (int m = 0; m < 4; ++m)
#pragma unroll
      for (int n = 0; n < 4; ++n)
        acc[m][n] = MFMA16(af[m], bfv[n], acc[m][n]);
    __syncthreads();
  }

#pragma unroll
  for (int m = 0; m < 4; ++m) {
    const int s0 = row0 + wr * 64 + m * 16 + g * 4;
#pragma unroll
    for (int n = 0; n < 4; ++n) {
      const int col = col0 + wc * 64 + n * 16 + r16;
      const float bv = bias[col];
#pragma unroll
      for (int r = 0; r < 4; ++r)
        out[(s0 + r) * HID + col] = acc[m][n][r] + bv;
    }
  }
}

extern "C" void kernel_launch(void* const* d_in, const int* in_sizes, int n_in,
                              void* d_out, int out_size, void* d_ws, size_t ws_size,
                              hipStream_t stream) {
  (void)in_sizes; (void)n_in; (void)out_size; (void)ws_size;
  const float* hidden = (const float*)d_in[0];
  const float* wqkv   = (const float*)d_in[2];
  const float* wdense = (const float*)d_in[3];
  const float* bdense = (const float*)d_in[4];
  float* out = (float*)d_out;

  char* ws = (char*)d_ws;
  unsigned short* hiddenB = (unsigned short*)(ws);
  unsigned short* wqkvB   = (unsigned short*)(ws + 16777216);
  unsigned short* wdenseB = (unsigned short*)(ws + 41943040);
  unsigned short* Qb      = (unsigned short*)(ws + 50331648);
  unsigned short* Kb      = (unsigned short*)(ws + 67108864);
  unsigned short* Vt      = (unsigned short*)(ws + 83886080);
  unsigned short* ctxB    = (unsigned short*)(ws + 100663296);

  cvt_kernel<<<8192, 256, 0, stream>>>(hidden, hiddenB, 8388608);
  cvt_kernel<<<12288, 256, 0, stream>>>(wqkv, wqkvB, 12582912);
  cvt_kernel<<<4096, 256, 0, stream>>>(wdense, wdenseB, 4194304);
  gemm_qkv_kernel<<<1536, 256, 0, stream>>>(hiddenB, wqkvB, Qb, Kb, Vt);
  rope_kernel<<<4096, 256, 0, stream>>>(Qb, Kb);
  attn_kernel<<<512, 256, 0, stream>>>(Qb, Kb, Vt, ctxB);
  gemm_dense_kernel<<<512, 256, 0, stream>>>(ctxB, wdenseB, bdense, out);
}

// Round 5
// 331.044 us; speedup vs baseline: 1.2099x; 1.0261x over previous
//
#include <hip/hip_runtime.h>

#define S_LEN 4096
#define HID   2048
#define NHEAD 16
#define HDIM  128
// 1/sqrt(128) * log2(e): Q pre-scale so softmax can use exp2 directly
#define QSCALE_L2E 0.12751664352f

typedef float  f32x4  __attribute__((ext_vector_type(4)));
typedef float  f32x16 __attribute__((ext_vector_type(16)));
typedef __bf16 bf16x8 __attribute__((ext_vector_type(8)));
typedef unsigned u32x4 __attribute__((ext_vector_type(4)));
typedef unsigned u32x2 __attribute__((ext_vector_type(2)));

#define MFMA16(a, b, c) __builtin_amdgcn_mfma_f32_16x16x32_bf16((a), (b), (c), 0, 0, 0)
#define MFMA32(a, b, c) __builtin_amdgcn_mfma_f32_32x32x16_bf16((a), (b), (c), 0, 0, 0)

__device__ __forceinline__ void gld16(const void* g, void* l) {
  __builtin_amdgcn_global_load_lds(
      (const __attribute__((address_space(1))) void*)(unsigned long long)(g),
      (__attribute__((address_space(3))) void*)(unsigned long long)(l),
      16, 0, 0);
}

__device__ __forceinline__ unsigned short f2bf(float f) {
  union { float f; unsigned u; } v; v.f = f;
  unsigned r = v.u + 0x7FFFu + ((v.u >> 16) & 1u);
  return (unsigned short)(r >> 16);
}
__device__ __forceinline__ float bf2f(unsigned short h) {
  union { unsigned u; float f; } v; v.u = ((unsigned)h) << 16;
  return v.f;
}
__device__ __forceinline__ unsigned cvtpk_bf16(float a, float b) {
  unsigned r;
  asm("v_cvt_pk_bf16_f32 %0, %1, %2" : "=v"(r) : "v"(a), "v"(b));
  return r;
}
// lane l<32 / l>=32 exchange: ret[0] = {a.lo || b.lo}, ret[1] = {a.hi || b.hi}
__device__ __forceinline__ u32x2 pls(unsigned a, unsigned b) {
  return __builtin_amdgcn_permlane32_swap(a, b, false, false);
}
__device__ __forceinline__ float asf(unsigned u) { return __builtin_bit_cast(float, u); }
__device__ __forceinline__ unsigned asu(float f) { return __builtin_bit_cast(unsigned, f); }

// ---------------- f32 -> bf16 conversion ----------------
__global__ __launch_bounds__(256) void cvt_kernel(const float* __restrict__ src,
                                                  unsigned short* __restrict__ dst, int n) {
  int i = (blockIdx.x * 256 + threadIdx.x) * 4;
  if (i >= n) return;
  const float4 v = *(const float4*)(src + i);
  ushort4 o;
  o.x = f2bf(v.x); o.y = f2bf(v.y); o.z = f2bf(v.z); o.w = f2bf(v.w);
  *(ushort4*)(dst + i) = o;
}

// ---------------- QKV GEMM: C[4096,6144] = hidden[4096,2048] . wqkv[6144,2048]^T
__global__ __launch_bounds__(256, 3) void gemm_qkv_kernel(
    const unsigned short* __restrict__ A, const unsigned short* __restrict__ B,
    unsigned short* __restrict__ Qb, unsigned short* __restrict__ Kb,
    unsigned short* __restrict__ Vt) {
  __shared__ __align__(16) unsigned short As[2][128 * 32];
  __shared__ __align__(16) unsigned short Bs[2][128 * 32];
  const int K = HID;
  const int bid = ((int)blockIdx.x % 8) * 192 + (int)blockIdx.x / 8;
  const int bm = bid / 48, bn = bid % 48;
  const int row0 = bm * 128, col0 = bn * 128;
  const int tid = threadIdx.x;
  const int wid = tid >> 6, lane = tid & 63;
  const int g = lane >> 4, r16 = lane & 15;
  const int wr = wid >> 1, wc = wid & 1;

  f32x4 acc[4][4] = {};

  int srow[2], scol[2];
#pragma unroll
  for (int c = 0; c < 2; ++c) {
    int byteoff = (wid * 2 + c) * 1024 + lane * 16;
    srow[c] = byteoff >> 6;
    scol[c] = (byteoff & 63) >> 1;
  }

  auto stage = [&](int buf, int t) {
    const int k0 = t * 32;
#pragma unroll
    for (int c = 0; c < 2; ++c) {
      gld16(A + (row0 + srow[c]) * K + k0 + scol[c], &As[buf][(wid * 2 + c) * 512]);
      gld16(B + (col0 + srow[c]) * K + k0 + scol[c], &Bs[buf][(wid * 2 + c) * 512]);
    }
  };

  const int nt = K / 32;
  stage(0, 0);
  __syncthreads();
  for (int t = 0; t < nt; ++t) {
    const int cur = t & 1;
    if (t + 1 < nt) stage(cur ^ 1, t + 1);
    const char* as = (const char*)As[cur];
    const char* bs = (const char*)Bs[cur];
    bf16x8 af[4], bfv[4];
#pragma unroll
    for (int m = 0; m < 4; ++m)
      af[m] = *(const bf16x8*)(as + (wr * 64 + m * 16 + r16) * 64 + g * 16);
#pragma unroll
    for (int n = 0; n < 4; ++n)
      bfv[n] = *(const bf16x8*)(bs + (wc * 64 + n * 16 + r16) * 64 + g * 16);
#pragma unroll
    for (int m = 0; m < 4; ++m)
#pragma unroll
      for (int n = 0; n < 4; ++n)
        acc[m][n] = MFMA16(af[m], bfv[n], acc[m][n]);
    __syncthreads();
  }

  const int type = bn % 3, p = bn / 3;
#pragma unroll
  for (int m = 0; m < 4; ++m) {
    const int s0 = row0 + wr * 64 + m * 16 + g * 4;
#pragma unroll
    for (int n = 0; n < 4; ++n) {
      const int d = wc * 64 + n * 16 + r16;
      if (type == 0) {
#pragma unroll
        for (int r = 0; r < 4; ++r)
          Qb[(p * S_LEN + s0 + r) * HDIM + d] = f2bf(acc[m][n][r] * QSCALE_L2E);
      } else if (type == 1) {
#pragma unroll
        for (int r = 0; r < 4; ++r)
          Kb[(p * S_LEN + s0 + r) * HDIM + d] = f2bf(acc[m][n][r]);
      } else {
        ushort4 o;
        o.x = f2bf(acc[m][n][0]); o.y = f2bf(acc[m][n][1]);
        o.z = f2bf(acc[m][n][2]); o.w = f2bf(acc[m][n][3]);
        *(ushort4*)(Vt + (p * HDIM + d) * S_LEN + s0) = o;
      }
    }
  }
}

// ---------------- partial RoPE (NeoX, first 32 dims) ----------------
__global__ __launch_bounds__(256) void rope_kernel(unsigned short* __restrict__ Qb,
                                                   unsigned short* __restrict__ Kb) {
  const int idx = blockIdx.x * 256 + threadIdx.x;
  const int p = idx >> 16, rem = idx & 65535, s = rem >> 4, d = rem & 15;
  const float invf = exp2f(-(float)d * (13.287712379549449f / 16.0f));
  const float ang = (float)s * invf;
  const float c = cosf(ang), sn = sinf(ang);
  const int base = (p * S_LEN + s) * HDIM;
  {
    float x = bf2f(Qb[base + d]), y = bf2f(Qb[base + d + 16]);
    Qb[base + d]      = f2bf(x * c - y * sn);
    Qb[base + d + 16] = f2bf(y * c + x * sn);
  }
  {
    float x = bf2f(Kb[base + d]), y = bf2f(Kb[base + d + 16]);
    Kb[base + d]      = f2bf(x * c - y * sn);
    Kb[base + d + 16] = f2bf(y * c + x * sn);
  }
}

// ---------------- causal flash attention, swapped-QK 32x32, 2-stage pipeline ----
// grid 512: head = b&15; qt = b<256 ? b>>4 : 47-(b>>4); 4 waves x 32 q-rows,
// KVBLK=64, 2 blocks/CU. Pipeline: QK(t+1) issued before softmax(t)+PV(t).
// K double-buffered (16KB x2), V triple-buffered (16KB x3): stage target is
// provably disjoint from every same-interval read. LDS 80KB -> 2 blocks/CU.
__global__ __launch_bounds__(256, 2) void attn_kernel(
    const unsigned short* __restrict__ Qb, const unsigned short* __restrict__ Kb,
    const unsigned short* __restrict__ Vt, unsigned short* __restrict__ Ctx) {
  __shared__ __align__(16) unsigned char sm[81920];  // K 2x16K | V 3x16K
  const int b = (int)blockIdx.x;
  const int p = b & 15;
  const int qt = (b < 256) ? (b >> 4) : 47 - (b >> 4);
  const int tid = threadIdx.x, wid = tid >> 6, lane = tid & 63;
  const int l31 = lane & 31, hi = lane >> 5;
  const int xr = (l31 & 7) << 4;

  const int q0w = qt * 128 + wid * 32;
  const int qg = q0w + l31;
  const int nt = 2 * (qt + 1);   // always even
  const int np = nt >> 1;

  auto stage = [&](int t, int ko, int vo) {
    const unsigned short* kb = Kb + (p * S_LEN + t * 64) * HDIM;
    const unsigned short* vb = Vt + p * HDIM * S_LEN + t * 64;
#pragma unroll
    for (int c = 0; c < 4; ++c) {
      const int chunk = c * 256 + tid;
      const int byteoff = chunk * 16;
      const int j = byteoff >> 8, cbK = (byteoff >> 4) & 15;
      gld16(kb + j * HDIM + (cbK ^ (j & 7)) * 8, sm + ko + chunk * 16);
      const int dd = byteoff >> 7, cbV = (byteoff >> 4) & 7;
      gld16(vb + dd * S_LEN + (cbV ^ (dd & 7)) * 8, sm + vo + chunk * 16);
    }
  };

  bf16x8 qf[8];
  f32x16 acc[4] = {};
  float m_s = -1e30f, l_s = 0.f;

  auto qk = [&](f32x16& s0, f32x16& s1, const unsigned char* kl) {
    __builtin_amdgcn_s_setprio(1);
#pragma unroll
    for (int dd = 0; dd < 8; ++dd) {
      bf16x8 k0 = *(const bf16x8*)(kl + l31 * 256 + (((dd * 2 + hi) << 4) ^ xr));
      bf16x8 k1 = *(const bf16x8*)(kl + (32 + l31) * 256 + (((dd * 2 + hi) << 4) ^ xr));
      s0 = MFMA32(k0, qf[dd], s0);
      s1 = MFMA32(k1, qf[dd], s1);
    }
    __builtin_amdgcn_s_setprio(0);
  };

  auto smpv = [&](f32x16& s0, f32x16& s1, int t, int vo) {
    const unsigned char* vl = sm + vo;
    // causal mask (only near-diagonal tiles)
    if (t * 64 + 63 > q0w) {
#pragma unroll
      for (int r = 0; r < 16; ++r) {
        const int kv0 = t * 64 + ((r & 3) + 8 * (r >> 2)) + 4 * hi;
        if (kv0 > qg) s0[r] = -1e30f;
        if (kv0 + 32 > qg) s1[r] = -1e30f;
      }
    }
    // row max: local tree + partner exchange
    float mx[16];
#pragma unroll
    for (int r = 0; r < 16; ++r) mx[r] = fmaxf(s0[r], s1[r]);
#pragma unroll
    for (int r = 0; r < 8; ++r) mx[r] = fmaxf(mx[r], mx[r + 8]);
#pragma unroll
    for (int r = 0; r < 4; ++r) mx[r] = fmaxf(mx[r], mx[r + 4]);
    mx[0] = fmaxf(fmaxf(mx[0], mx[2]), fmaxf(mx[1], mx[3]));
    float pm;
    {
      u32x2 e = pls(asu(mx[0]), asu(mx[0]));
      pm = fmaxf(asf(e.x), asf(e.y));
    }
    // defer-max rescale (THR = 8 nats = 11.5 in log2 domain)
    if (__any(pm > m_s + 11.5f)) {
      const float mn = fmaxf(m_s, pm);
      const float scl = exp2f(m_s - mn);
#pragma unroll
      for (int d32 = 0; d32 < 4; ++d32)
#pragma unroll
        for (int r = 0; r < 16; ++r) acc[d32][r] *= scl;
      l_s *= scl;
      m_s = mn;
    }
    // P = exp2(S - m)
#pragma unroll
    for (int r = 0; r < 16; ++r) {
      s0[r] = exp2f(s0[r] - m_s);
      s1[r] = exp2f(s1[r] - m_s);
    }
    // pack P^T into PV B-fragments (cross-half via permlane32_swap)
    bf16x8 pf[4];
#define PACKB(B, SV, base)                                                        \
    {                                                                             \
      unsigned X0 = cvtpk_bf16(SV[base + 0], SV[base + 1]);                       \
      unsigned X1 = cvtpk_bf16(SV[base + 2], SV[base + 3]);                       \
      unsigned Y0 = cvtpk_bf16(SV[base + 4], SV[base + 5]);                       \
      unsigned Y1 = cvtpk_bf16(SV[base + 6], SV[base + 7]);                       \
      u32x2 e0 = pls(X0, Y0);                                                     \
      u32x2 e1 = pls(X1, Y1);                                                     \
      u32x4 pw;                                                                   \
      pw.x = e0.x; pw.y = e1.x; pw.z = e0.y; pw.w = e1.y;                         \
      pf[B] = __builtin_bit_cast(bf16x8, pw);                                     \
    }
    PACKB(0, s0, 0)
    PACKB(1, s0, 8)
    PACKB(2, s1, 0)
    PACKB(3, s1, 8)
#undef PACKB
    // O^T[d][q] += V^T . P^T
    __builtin_amdgcn_s_setprio(1);
#pragma unroll
    for (int d32 = 0; d32 < 4; ++d32) {
#pragma unroll
      for (int bb = 0; bb < 4; ++bb) {
        bf16x8 vf = *(const bf16x8*)(vl + (d32 * 32 + l31) * 128 + (((bb * 2 + hi) << 4) ^ xr));
        acc[d32] = MFMA32(vf, pf[bb], acc[d32]);
      }
    }
    __builtin_amdgcn_s_setprio(0);
    // row sum (after PV issue: VALU overlaps MFMA)
    float s_[8];
#pragma unroll
    for (int r = 0; r < 8; ++r) s_[r] = (s0[r] + s0[r + 8]) + (s1[r] + s1[r + 8]);
#pragma unroll
    for (int r = 0; r < 4; ++r) s_[r] += s_[r + 4];
    const float rs = (s_[0] + s_[1]) + (s_[2] + s_[3]);
    u32x2 e = pls(asu(rs), asu(rs));
    l_s += asf(e.x) + asf(e.y);
  };

  // prologue: stage tiles 0,1; QK(0)
  stage(0, 0, 32768);
  stage(1, 16384, 49152);
  {
    const unsigned short* qp_ = Qb + (p * S_LEN + qg) * HDIM + hi * 8;
#pragma unroll
    for (int dd = 0; dd < 8; ++dd) qf[dd] = *(const bf16x8*)(qp_ + dd * 16);
  }
  int vcur = 32768, vnext = 49152, vstage = 65536;
  __syncthreads();
  f32x16 sA0 = {}, sA1 = {};
  qk(sA0, sA1, sm);                       // QK(0) from Kbuf0
  __syncthreads();                        // isolate QK(0) reads from stage->Kbuf0

  for (int tt = 0; tt < np; ++tt) {
    const bool more = (tt + 1 < np);
    const int t = 2 * tt;
    // ---- half A (tile t): QK(t+1) from Kbuf1; stage(t+2)->Kbuf0,vstage
    f32x16 sB0 = {}, sB1 = {};
    qk(sB0, sB1, sm + 16384);             // t+1 <= nt-1 always
    if (more) stage(t + 2, 0, vstage);
    smpv(sA0, sA1, t, vcur);
    { int tmp = vcur; vcur = vnext; vnext = vstage; vstage = tmp; }
    __syncthreads();
    // ---- half B (tile t+1): QK(t+2) from Kbuf0; stage(t+3)->Kbuf1,vstage
    if (more) {
      sA0 = {}; sA1 = {};
      qk(sA0, sA1, sm);
      stage(t + 3, 16384, vstage);
    }
    smpv(sB0, sB1, t + 1, vcur);
    { int tmp = vcur; vcur = vnext; vnext = vstage; vstage = tmp; }
    __syncthreads();
  }

  // epilogue
  const float inv = 1.0f / l_s;
  unsigned short* cbase = Ctx + qg * HID + p * HDIM;
#pragma unroll
  for (int d32 = 0; d32 < 4; ++d32)
#pragma unroll
    for (int r = 0; r < 16; ++r) {
      const int d = d32 * 32 + ((r & 3) + 8 * (r >> 2)) + 4 * hi;
      cbase[d] = f2bf(acc[d32][r] * inv);
    }
}

// ---------------- dense GEMM: out[4096,2048] = ctx . wdense^T + bias (f32 out) ----------------
__global__ __launch_bounds__(256, 3) void gemm_dense_kernel(
    const unsigned short* __restrict__ A, const unsigned short* __restrict__ B,
    const float* __restrict__ bias, float* __restrict__ out) {
  __shared__ __align__(16) unsigned short As[2][128 * 32];
  __shared__ __align__(16) unsigned short Bs[2][128 * 32];
  const int K = HID;
  const int bid = ((int)blockIdx.x % 8) * 64 + (int)blockIdx.x / 8;
  const int bm = bid / 16, bn = bid % 16;
  const int row0 = bm * 128, col0 = bn * 128;
  const int tid = threadIdx.x;
  const int wid = tid >> 6, lane = tid & 63;
  const int g = lane >> 4, r16 = lane & 15;
  const int wr = wid >> 1, wc = wid & 1;

  f32x4 acc[4][4] = {};

  int srow[2], scol[2];
#pragma unroll
  for (int c = 0; c < 2; ++c) {
    int byteoff = (wid * 2 + c) * 1024 + lane * 16;
    srow[c] = byteoff >> 6;
    scol[c] = (byteoff & 63) >> 1;
  }
  auto stage = [&](int buf, int t) {
    const int k0 = t * 32;
#pragma unroll
    for (int c = 0; c < 2; ++c) {
      gld16(A + (row0 + srow[c]) * K + k0 + scol[c], &As[buf][(wid * 2 + c) * 512]);
      gld16(B + (col0 + srow[c]) * K + k0 + scol[c], &Bs[buf][(wid * 2 + c) * 512]);
    }
  };

  const int nt = K / 32;
  stage(0, 0);
  __syncthreads();
  for (int t = 0; t < nt; ++t) {
    const int cur = t & 1;
    if (t + 1 < nt) stage(cur ^ 1, t + 1);
    const char* as = (const char*)As[cur];
    const char* bs = (const char*)Bs[cur];
    bf16x8 af[4], bfv[4];
#pragma unroll
    for (int m = 0; m < 4; ++m)
      af[m] = *(const bf16x8*)(as + (wr * 64 + m * 16 + r16) * 64 + g * 16);
#pragma unroll
    for (int n = 0; n < 4; ++n)
      bfv[n] = *(const bf16x8*)(bs + (wc * 64 + n * 16 + r16) * 64 + g * 16);
#pragma unroll
    for (int m = 0; m < 4; ++m)
#pragma unroll
      for (int n = 0; n < 4; ++n)
        acc[m][n] = MFMA16(af[m], bfv[n], acc[m][n]);
    __syncthreads();
  }

#pragma unroll
  for (int m = 0; m < 4; ++m) {
    const int s0 = row0 + wr * 64 + m * 16 + g * 4;
#pragma unroll
    for (int n = 0; n < 4; ++n) {
      const int col = col0 + wc * 64 + n * 16 + r16;
      const float bv = bias[col];
#pragma unroll
      for (int r = 0; r < 4; ++r)
        out[(s0 + r) * HID + col] = acc[m][n][r] + bv;
    }
  }
}

extern "C" void kernel_launch(void* const* d_in, const int* in_sizes, int n_in,
                              void* d_out, int out_size, void* d_ws, size_t ws_size,
                              hipStream_t stream) {
  (void)in_sizes; (void)n_in; (void)out_size; (void)ws_size;
  const float* hidden = (const float*)d_in[0];
  const float* wqkv   = (const float*)d_in[2];
  const float* wdense = (const float*)d_in[3];
  const float* bdense = (const float*)d_in[4];
  float* out = (float*)d_out;

  char* ws = (char*)d_ws;
  unsigned short* hiddenB = (unsigned short*)(ws);
  unsigned short* wqkvB   = (unsigned short*)(ws + 16777216);
  unsigned short* wdenseB = (unsigned short*)(ws + 41943040);
  unsigned short* Qb      = (unsigned short*)(ws + 50331648);
  unsigned short* Kb      = (unsigned short*)(ws + 67108864);
  unsigned short* Vt      = (unsigned short*)(ws + 83886080);
  unsigned short* ctxB    = (unsigned short*)(ws + 100663296);

  cvt_kernel<<<8192, 256, 0, stream>>>(hidden, hiddenB, 8388608);
  cvt_kernel<<<12288, 256, 0, stream>>>(wqkv, wqkvB, 12582912);
  cvt_kernel<<<4096, 256, 0, stream>>>(wdense, wdenseB, 4194304);
  gemm_qkv_kernel<<<1536, 256, 0, stream>>>(hiddenB, wqkvB, Qb, Kb, Vt);
  rope_kernel<<<4096, 256, 0, stream>>>(Qb, Kb);
  attn_kernel<<<512, 256, 0, stream>>>(Qb, Kb, Vt, ctxB);
  gemm_dense_kernel<<<512, 256, 0, stream>>>(ctxB, wdenseB, bdense, out);
}

// Round 6
// 316.234 us; speedup vs baseline: 1.2665x; 1.0468x over previous
//
#include <hip/hip_runtime.h>

#define S_LEN 4096
#define HID   2048
#define NHEAD 16
#define HDIM  128
// 1/sqrt(128) * log2(e): Q pre-scale so softmax can use exp2 directly
#define QSCALE_L2E 0.12751664352f

typedef float  f32x4  __attribute__((ext_vector_type(4)));
typedef float  f32x16 __attribute__((ext_vector_type(16)));
typedef __bf16 bf16x8 __attribute__((ext_vector_type(8)));
typedef unsigned u32x4 __attribute__((ext_vector_type(4)));
typedef unsigned u32x2 __attribute__((ext_vector_type(2)));

#define MFMA16(a, b, c) __builtin_amdgcn_mfma_f32_16x16x32_bf16((a), (b), (c), 0, 0, 0)
#define MFMA32(a, b, c) __builtin_amdgcn_mfma_f32_32x32x16_bf16((a), (b), (c), 0, 0, 0)

__device__ __forceinline__ void gld16(const void* g, void* l) {
  __builtin_amdgcn_global_load_lds(
      (const __attribute__((address_space(1))) void*)(unsigned long long)(g),
      (__attribute__((address_space(3))) void*)(unsigned long long)(l),
      16, 0, 0);
}

__device__ __forceinline__ unsigned short f2bf(float f) {
  union { float f; unsigned u; } v; v.f = f;
  unsigned r = v.u + 0x7FFFu + ((v.u >> 16) & 1u);
  return (unsigned short)(r >> 16);
}
__device__ __forceinline__ float bf2f(unsigned short h) {
  union { unsigned u; float f; } v; v.u = ((unsigned)h) << 16;
  return v.f;
}
__device__ __forceinline__ unsigned cvtpk_bf16(float a, float b) {
  unsigned r;
  asm("v_cvt_pk_bf16_f32 %0, %1, %2" : "=v"(r) : "v"(a), "v"(b));
  return r;
}
// lane l<32 / l>=32 exchange: ret[0] = {a.lo || b.lo}, ret[1] = {a.hi || b.hi}
__device__ __forceinline__ u32x2 pls(unsigned a, unsigned b) {
  return __builtin_amdgcn_permlane32_swap(a, b, false, false);
}
__device__ __forceinline__ float asf(unsigned u) { return __builtin_bit_cast(float, u); }
__device__ __forceinline__ unsigned asu(float f) { return __builtin_bit_cast(unsigned, f); }

// ---------------- f32 -> bf16 conversion ----------------
__global__ __launch_bounds__(256) void cvt_kernel(const float* __restrict__ src,
                                                  unsigned short* __restrict__ dst, int n) {
  int i = (blockIdx.x * 256 + threadIdx.x) * 4;
  if (i >= n) return;
  const float4 v = *(const float4*)(src + i);
  ushort4 o;
  o.x = f2bf(v.x); o.y = f2bf(v.y); o.z = f2bf(v.z); o.w = f2bf(v.w);
  *(ushort4*)(dst + i) = o;
}

// ---------------- deep-pipelined GEMM, BM=256 x BN=128 x BK=64, 512 thr ----------
// C[M,n] = A[M,K] . B[n,K]^T.  EPI 0: QKV scatter epilogue (768 blocks);
// EPI 1: f32 + bias epilogue (256 blocks).  2 phases per K-tile, raw barriers,
// single vmcnt(0) per K-tile placed after the last MFMA cluster; stages always
// write the non-read buffer; XOR swizzle (r&7)<<4 on stage source + ds_read.
template <int EPI>
__global__ __launch_bounds__(512, 2) void gemm256_kernel(
    const unsigned short* __restrict__ A, const unsigned short* __restrict__ B,
    unsigned short* __restrict__ Qb, unsigned short* __restrict__ Kb,
    unsigned short* __restrict__ Vt,
    const float* __restrict__ bias, float* __restrict__ out) {
  __shared__ __align__(16) unsigned char sm[98304];  // 2 x (A 32K | B 16K)
  constexpr int K = HID;
  constexpr int NT = K / 64;
  constexpr int NB = (EPI == 0) ? 768 : 256;
  const int b = (int)blockIdx.x;
  const int swz = (b & 7) * (NB >> 3) + (b >> 3);   // XCD swizzle (NB % 8 == 0)
  const int bm = swz & 15, bn = swz >> 4;
  const int row0 = bm * 256, col0 = bn * 128;
  const int tid = threadIdx.x;
  const int wid = tid >> 6, lane = tid & 63;
  const int g = lane >> 4, r16 = lane & 15;
  const int wm = wid >> 1, wn = wid & 1;

  auto stageA = [&](int t) {
    const int bufo = (t & 1) * 49152;
    const int k0 = t * 64;
#pragma unroll
    for (int h = 0; h < 2; ++h)
#pragma unroll
      for (int cc = 0; cc < 2; ++cc) {
        const int chunk = cc * 512 + tid;
        const int r = chunk >> 3, c7 = chunk & 7;
        gld16(A + (row0 + h * 128 + r) * K + k0 + ((c7 ^ (r & 7)) << 3),
              sm + bufo + h * 16384 + chunk * 16);
      }
  };
  auto stageB = [&](int t) {
    const int bufo = (t & 1) * 49152;
    const int k0 = t * 64;
#pragma unroll
    for (int cc = 0; cc < 2; ++cc) {
      const int chunk = cc * 512 + tid;
      const int r = chunk >> 3, c7 = chunk & 7;
      gld16(B + (col0 + r) * K + k0 + ((c7 ^ (r & 7)) << 3),
            sm + bufo + 32768 + chunk * 16);
    }
  };

  f32x4 acc[4][4] = {};

  int aoff[4], boff[4];
#pragma unroll
  for (int m = 0; m < 4; ++m) {
    const int r = (wm & 1) * 64 + m * 16 + r16;
    aoff[m] = (wm >> 1) * 16384 + r * 128 + ((g * 16) ^ ((r & 7) << 4));
  }
#pragma unroll
  for (int n = 0; n < 4; ++n) {
    const int r = wn * 64 + n * 16 + r16;
    boff[n] = 32768 + r * 128 + ((g * 16) ^ ((r & 7) << 4));
  }

  stageA(0); stageB(0);
  asm volatile("s_waitcnt vmcnt(0)" ::: "memory");
  __builtin_amdgcn_s_barrier();

  for (int t = 0; t < NT; ++t) {
    const int bufo = (t & 1) * 49152;
    const bool st = (t + 1 < NT);
    bf16x8 af[4], bfv[4];
    // ---- phase kk=0
#pragma unroll
    for (int m = 0; m < 4; ++m) af[m] = *(const bf16x8*)(sm + bufo + aoff[m]);
#pragma unroll
    for (int n = 0; n < 4; ++n) bfv[n] = *(const bf16x8*)(sm + bufo + boff[n]);
    if (st) stageA(t + 1);
    __builtin_amdgcn_s_barrier();
    asm volatile("s_waitcnt lgkmcnt(0)" ::: "memory");
    __builtin_amdgcn_s_setprio(1);
#pragma unroll
    for (int m = 0; m < 4; ++m)
#pragma unroll
      for (int n = 0; n < 4; ++n) acc[m][n] = MFMA16(af[m], bfv[n], acc[m][n]);
    __builtin_amdgcn_s_setprio(0);
    __builtin_amdgcn_s_barrier();
    // ---- phase kk=1
#pragma unroll
    for (int m = 0; m < 4; ++m) af[m] = *(const bf16x8*)(sm + bufo + (aoff[m] ^ 64));
#pragma unroll
    for (int n = 0; n < 4; ++n) bfv[n] = *(const bf16x8*)(sm + bufo + (boff[n] ^ 64));
    if (st) stageB(t + 1);
    __builtin_amdgcn_s_barrier();
    asm volatile("s_waitcnt lgkmcnt(0)" ::: "memory");
    __builtin_amdgcn_s_setprio(1);
#pragma unroll
    for (int m = 0; m < 4; ++m)
#pragma unroll
      for (int n = 0; n < 4; ++n) acc[m][n] = MFMA16(af[m], bfv[n], acc[m][n]);
    __builtin_amdgcn_s_setprio(0);
    if (st) asm volatile("s_waitcnt vmcnt(0)" ::: "memory");
    __builtin_amdgcn_s_barrier();
  }

  if constexpr (EPI == 0) {
    const int type = bn % 3, p = bn / 3;
#pragma unroll
    for (int m = 0; m < 4; ++m) {
      const int s0 = row0 + wm * 64 + m * 16 + g * 4;
#pragma unroll
      for (int n = 0; n < 4; ++n) {
        const int d = wn * 64 + n * 16 + r16;
        if (type == 0) {
#pragma unroll
          for (int r = 0; r < 4; ++r)
            Qb[(p * S_LEN + s0 + r) * HDIM + d] = f2bf(acc[m][n][r] * QSCALE_L2E);
        } else if (type == 1) {
#pragma unroll
          for (int r = 0; r < 4; ++r)
            Kb[(p * S_LEN + s0 + r) * HDIM + d] = f2bf(acc[m][n][r]);
        } else {
          ushort4 o;
          o.x = f2bf(acc[m][n][0]); o.y = f2bf(acc[m][n][1]);
          o.z = f2bf(acc[m][n][2]); o.w = f2bf(acc[m][n][3]);
          *(ushort4*)(Vt + (p * HDIM + d) * S_LEN + s0) = o;
        }
      }
    }
  } else {
#pragma unroll
    for (int m = 0; m < 4; ++m) {
      const int s0 = row0 + wm * 64 + m * 16 + g * 4;
#pragma unroll
      for (int n = 0; n < 4; ++n) {
        const int col = col0 + wn * 64 + n * 16 + r16;
        const float bv = bias[col];
#pragma unroll
        for (int r = 0; r < 4; ++r)
          out[(s0 + r) * HID + col] = acc[m][n][r] + bv;
      }
    }
  }
}

// ---------------- partial RoPE (NeoX, first 32 dims) ----------------
__global__ __launch_bounds__(256) void rope_kernel(unsigned short* __restrict__ Qb,
                                                   unsigned short* __restrict__ Kb) {
  const int idx = blockIdx.x * 256 + threadIdx.x;
  const int p = idx >> 16, rem = idx & 65535, s = rem >> 4, d = rem & 15;
  const float invf = exp2f(-(float)d * (13.287712379549449f / 16.0f));
  const float ang = (float)s * invf;
  const float c = cosf(ang), sn = sinf(ang);
  const int base = (p * S_LEN + s) * HDIM;
  {
    float x = bf2f(Qb[base + d]), y = bf2f(Qb[base + d + 16]);
    Qb[base + d]      = f2bf(x * c - y * sn);
    Qb[base + d + 16] = f2bf(y * c + x * sn);
  }
  {
    float x = bf2f(Kb[base + d]), y = bf2f(Kb[base + d + 16]);
    Kb[base + d]      = f2bf(x * c - y * sn);
    Kb[base + d + 16] = f2bf(y * c + x * sn);
  }
}

// ---------------- causal flash attention, swapped-QK 32x32, 2-stage pipeline ----
__global__ __launch_bounds__(256, 2) void attn_kernel(
    const unsigned short* __restrict__ Qb, const unsigned short* __restrict__ Kb,
    const unsigned short* __restrict__ Vt, unsigned short* __restrict__ Ctx) {
  __shared__ __align__(16) unsigned char sm[81920];  // K 2x16K | V 3x16K
  const int b = (int)blockIdx.x;
  const int p = b & 15;
  const int qt = (b < 256) ? (b >> 4) : 47 - (b >> 4);
  const int tid = threadIdx.x, wid = tid >> 6, lane = tid & 63;
  const int l31 = lane & 31, hi = lane >> 5;
  const int xr = (l31 & 7) << 4;

  const int q0w = qt * 128 + wid * 32;
  const int qg = q0w + l31;
  const int nt = 2 * (qt + 1);   // always even
  const int np = nt >> 1;

  auto stage = [&](int t, int ko, int vo) {
    const unsigned short* kb = Kb + (p * S_LEN + t * 64) * HDIM;
    const unsigned short* vb = Vt + p * HDIM * S_LEN + t * 64;
#pragma unroll
    for (int c = 0; c < 4; ++c) {
      const int chunk = c * 256 + tid;
      const int byteoff = chunk * 16;
      const int j = byteoff >> 8, cbK = (byteoff >> 4) & 15;
      gld16(kb + j * HDIM + (cbK ^ (j & 7)) * 8, sm + ko + chunk * 16);
      const int dd = byteoff >> 7, cbV = (byteoff >> 4) & 7;
      gld16(vb + dd * S_LEN + (cbV ^ (dd & 7)) * 8, sm + vo + chunk * 16);
    }
  };

  bf16x8 qf[8];
  f32x16 acc[4] = {};
  float m_s = -1e30f, l_s = 0.f;

  auto qk = [&](f32x16& s0, f32x16& s1, const unsigned char* kl) {
    __builtin_amdgcn_s_setprio(1);
#pragma unroll
    for (int dd = 0; dd < 8; ++dd) {
      bf16x8 k0 = *(const bf16x8*)(kl + l31 * 256 + (((dd * 2 + hi) << 4) ^ xr));
      bf16x8 k1 = *(const bf16x8*)(kl + (32 + l31) * 256 + (((dd * 2 + hi) << 4) ^ xr));
      s0 = MFMA32(k0, qf[dd], s0);
      s1 = MFMA32(k1, qf[dd], s1);
    }
    __builtin_amdgcn_s_setprio(0);
  };

  auto smpv = [&](f32x16& s0, f32x16& s1, int t, int vo) {
    const unsigned char* vl = sm + vo;
    if (t * 64 + 63 > q0w) {
#pragma unroll
      for (int r = 0; r < 16; ++r) {
        const int kv0 = t * 64 + ((r & 3) + 8 * (r >> 2)) + 4 * hi;
        if (kv0 > qg) s0[r] = -1e30f;
        if (kv0 + 32 > qg) s1[r] = -1e30f;
      }
    }
    float mx[16];
#pragma unroll
    for (int r = 0; r < 16; ++r) mx[r] = fmaxf(s0[r], s1[r]);
#pragma unroll
    for (int r = 0; r < 8; ++r) mx[r] = fmaxf(mx[r], mx[r + 8]);
#pragma unroll
    for (int r = 0; r < 4; ++r) mx[r] = fmaxf(mx[r], mx[r + 4]);
    mx[0] = fmaxf(fmaxf(mx[0], mx[2]), fmaxf(mx[1], mx[3]));
    float pm;
    {
      u32x2 e = pls(asu(mx[0]), asu(mx[0]));
      pm = fmaxf(asf(e.x), asf(e.y));
    }
    if (__any(pm > m_s + 11.5f)) {
      const float mn = fmaxf(m_s, pm);
      const float scl = exp2f(m_s - mn);
#pragma unroll
      for (int d32 = 0; d32 < 4; ++d32)
#pragma unroll
        for (int r = 0; r < 16; ++r) acc[d32][r] *= scl;
      l_s *= scl;
      m_s = mn;
    }
#pragma unroll
    for (int r = 0; r < 16; ++r) {
      s0[r] = exp2f(s0[r] - m_s);
      s1[r] = exp2f(s1[r] - m_s);
    }
    bf16x8 pf[4];
#define PACKB(B, SV, base)                                                        \
    {                                                                             \
      unsigned X0 = cvtpk_bf16(SV[base + 0], SV[base + 1]);                       \
      unsigned X1 = cvtpk_bf16(SV[base + 2], SV[base + 3]);                       \
      unsigned Y0 = cvtpk_bf16(SV[base + 4], SV[base + 5]);                       \
      unsigned Y1 = cvtpk_bf16(SV[base + 6], SV[base + 7]);                       \
      u32x2 e0 = pls(X0, Y0);                                                     \
      u32x2 e1 = pls(X1, Y1);                                                     \
      u32x4 pw;                                                                   \
      pw.x = e0.x; pw.y = e1.x; pw.z = e0.y; pw.w = e1.y;                         \
      pf[B] = __builtin_bit_cast(bf16x8, pw);                                     \
    }
    PACKB(0, s0, 0)
    PACKB(1, s0, 8)
    PACKB(2, s1, 0)
    PACKB(3, s1, 8)
#undef PACKB
    __builtin_amdgcn_s_setprio(1);
#pragma unroll
    for (int d32 = 0; d32 < 4; ++d32) {
#pragma unroll
      for (int bb = 0; bb < 4; ++bb) {
        bf16x8 vf = *(const bf16x8*)(vl + (d32 * 32 + l31) * 128 + (((bb * 2 + hi) << 4) ^ xr));
        acc[d32] = MFMA32(vf, pf[bb], acc[d32]);
      }
    }
    __builtin_amdgcn_s_setprio(0);
    float s_[8];
#pragma unroll
    for (int r = 0; r < 8; ++r) s_[r] = (s0[r] + s0[r + 8]) + (s1[r] + s1[r + 8]);
#pragma unroll
    for (int r = 0; r < 4; ++r) s_[r] += s_[r + 4];
    const float rs = (s_[0] + s_[1]) + (s_[2] + s_[3]);
    u32x2 e = pls(asu(rs), asu(rs));
    l_s += asf(e.x) + asf(e.y);
  };

  stage(0, 0, 32768);
  stage(1, 16384, 49152);
  {
    const unsigned short* qp_ = Qb + (p * S_LEN + qg) * HDIM + hi * 8;
#pragma unroll
    for (int dd = 0; dd < 8; ++dd) qf[dd] = *(const bf16x8*)(qp_ + dd * 16);
  }
  int vcur = 32768, vnext = 49152, vstage = 65536;
  __syncthreads();
  f32x16 sA0 = {}, sA1 = {};
  qk(sA0, sA1, sm);
  __syncthreads();

  for (int tt = 0; tt < np; ++tt) {
    const bool more = (tt + 1 < np);
    const int t = 2 * tt;
    f32x16 sB0 = {}, sB1 = {};
    qk(sB0, sB1, sm + 16384);
    if (more) stage(t + 2, 0, vstage);
    smpv(sA0, sA1, t, vcur);
    { int tmp = vcur; vcur = vnext; vnext = vstage; vstage = tmp; }
    __syncthreads();
    if (more) {
      sA0 = {}; sA1 = {};
      qk(sA0, sA1, sm);
      stage(t + 3, 16384, vstage);
    }
    smpv(sB0, sB1, t + 1, vcur);
    { int tmp = vcur; vcur = vnext; vnext = vstage; vstage = tmp; }
    __syncthreads();
  }

  const float inv = 1.0f / l_s;
  unsigned short* cbase = Ctx + qg * HID + p * HDIM;
#pragma unroll
  for (int d32 = 0; d32 < 4; ++d32)
#pragma unroll
    for (int r = 0; r < 16; ++r) {
      const int d = d32 * 32 + ((r & 3) + 8 * (r >> 2)) + 4 * hi;
      cbase[d] = f2bf(acc[d32][r] * inv);
    }
}

extern "C" void kernel_launch(void* const* d_in, const int* in_sizes, int n_in,
                              void* d_out, int out_size, void* d_ws, size_t ws_size,
                              hipStream_t stream) {
  (void)in_sizes; (void)n_in; (void)out_size; (void)ws_size;
  const float* hidden = (const float*)d_in[0];
  const float* wqkv   = (const float*)d_in[2];
  const float* wdense = (const float*)d_in[3];
  const float* bdense = (const float*)d_in[4];
  float* out = (float*)d_out;

  char* ws = (char*)d_ws;
  unsigned short* hiddenB = (unsigned short*)(ws);
  unsigned short* wqkvB   = (unsigned short*)(ws + 16777216);
  unsigned short* wdenseB = (unsigned short*)(ws + 41943040);
  unsigned short* Qb      = (unsigned short*)(ws + 50331648);
  unsigned short* Kb      = (unsigned short*)(ws + 67108864);
  unsigned short* Vt      = (unsigned short*)(ws + 83886080);
  unsigned short* ctxB    = (unsigned short*)(ws + 100663296);

  cvt_kernel<<<8192, 256, 0, stream>>>(hidden, hiddenB, 8388608);
  cvt_kernel<<<12288, 256, 0, stream>>>(wqkv, wqkvB, 12582912);
  cvt_kernel<<<4096, 256, 0, stream>>>(wdense, wdenseB, 4194304);
  gemm256_kernel<0><<<768, 512, 0, stream>>>(hiddenB, wqkvB, Qb, Kb, Vt, nullptr, nullptr);
  rope_kernel<<<4096, 256, 0, stream>>>(Qb, Kb);
  attn_kernel<<<512, 256, 0, stream>>>(Qb, Kb, Vt, ctxB);
  gemm256_kernel<1><<<256, 512, 0, stream>>>(ctxB, wdenseB, nullptr, nullptr, nullptr, bdense, out);
}